// Round 15
// baseline (546.945 us; speedup 1.0000x reference)
//
#include <hip/hip_runtime.h>
#include <hip/hip_bf16.h>

// Problem constants (fixed by setup_inputs)
constexpr int B_ = 8;
constexpr int C_ = 64;      // input channels = KC = VC = 64
constexpr int N_ = 65536;   // H*W = 256*256
constexpr int HW_ = 256;
constexpr float EPSF = 1e-6f;
constexpr int STATS = 4224; // 4096 matrix + 64 ksum + 64 vsum
constexpr int CHUNKS = 64;  // stats blocks per (branch,batch)

typedef __attribute__((ext_vector_type(8))) short bf16x8;
typedef __attribute__((ext_vector_type(4))) float f32x4;

// RNE fp32 -> bf16 bits, pure bit arithmetic (no address-taken locals)
__device__ __forceinline__ unsigned short f2bf(float f) {
  const unsigned u = __float_as_uint(f);
  return (unsigned short)((u + 0x7fffu + ((u >> 16) & 1u)) >> 16);
}

// ================================================================
// prep_proj: K/V projection weights -> MFMA A-fragment order, bf16.
// WK[r(2)][kv(2)][ot(4)][ks(2)][lane(64)][j(8)]  (unchanged)
// ================================================================
__global__ void prep_proj_kernel(const float* __restrict__ k1w,
                                 const float* __restrict__ v1w,
                                 const float* __restrict__ k2w,
                                 const float* __restrict__ v2w,
                                 unsigned short* __restrict__ WK) {
  const int e = blockIdx.x * 256 + threadIdx.x;   // 16384 total
  if (e >= 16384) return;
  const int j    = e & 7;
  const int lane = (e >> 3) & 63;
  const int ks   = (e >> 9) & 1;
  const int ot   = (e >> 10) & 3;
  const int kv   = (e >> 12) & 1;
  const int r    = (e >> 13) & 1;
  const int m    = ot * 16 + (lane & 15);
  const int ch   = ks * 32 + ((lane >> 4) & 3) * 8 + j;
  const float* w = r ? (kv ? v2w : k2w) : (kv ? v1w : k1w);
  WK[e] = f2bf(w[m * 64 + ch]);
}

// ================================================================
// qw_prep: Q projection weights -> A-frag order, bf16 HI/LO planes.
// ================================================================
__global__ void qw_prep_kernel(const float* __restrict__ q1w,
                               const float* __restrict__ q2w,
                               unsigned short* __restrict__ QWA) {
  const int e = blockIdx.x * 256 + threadIdx.x;
  if (e >= 16384) return;
  const int j    = e & 7;
  const int lane = (e >> 3) & 63;
  const int ks   = (e >> 9) & 1;
  const int ot   = (e >> 10) & 3;
  const int v    = (e >> 12) & 1;
  const int r    = (e >> 13) & 1;
  const int m    = ot * 16 + (lane & 15);
  const int ch   = ks * 32 + ((lane >> 4) & 3) * 8 + j;
  const float val = (r ? q2w : q1w)[m * 64 + ch];
  unsigned short h = f2bf(val);
  if (v) h = f2bf(val - __uint_as_float((unsigned)h << 16));
  QWA[e] = h;
}

// ================================================================
// rm_prep: rm (= derived[bb][o*64+m]) -> A-frag order bf16 HI/LO.
// ================================================================
__global__ void rm_prep_kernel(const float* __restrict__ derived,
                               unsigned short* __restrict__ RMA) {
  const int e = blockIdx.x * 256 + threadIdx.x;   // 131072 total
  if (e >= 131072) return;
  const int j    = e & 7;
  const int lane = (e >> 3) & 63;
  const int ks   = (e >> 9) & 1;
  const int ot   = (e >> 10) & 3;
  const int v    = (e >> 12) & 1;
  const int bb   = e >> 13;
  const int o    = ot * 16 + (lane & 15);
  const int m    = ks * 32 + ((lane >> 4) & 3) * 8 + j;
  const float val = derived[(size_t)bb * STATS + o * 64 + m];
  unsigned short h = f2bf(val);
  if (v) h = f2bf(val - __uint_as_float((unsigned)h << 16));
  RMA[e] = h;
}

// ================================================================
// Pass 1 (MFMA stats).
// ROUND-15: T14 prefetch (issue-early/write-late) on the x staging
// + barrier reduction 3 -> 2 per iter (loop-top barrier was
// redundant: write Xs(i) conflicts only with proj(i-1) reads of Xs,
// fenced by iter i-1's post-Vs barrier; matrix never reads Xs).
// ================================================================
__global__ __launch_bounds__(256, 2) void stats_mfma_kernel(
    const float* __restrict__ t1, const float* __restrict__ t2,
    const float* __restrict__ k1b, const float* __restrict__ v1b,
    const float* __restrict__ k2b, const float* __restrict__ v2b,
    const unsigned short* __restrict__ WK,
    float* __restrict__ partials)
{
  const int chunk = blockIdx.x;
  const int b = blockIdx.y;
  const int r = blockIdx.z;
  const float* x  = (r ? t2 : t1) + (size_t)b * C_ * N_;
  const float* kb = r ? k2b : k1b;
  const float* vb = r ? v2b : v1b;
  const unsigned short* WKr = WK + r * 8192;

  __shared__ unsigned short Xs[64 * 72];
  __shared__ unsigned short Ks[64 * 72];
  __shared__ unsigned short Vs[64 * 72];

  const int t  = threadIdx.x;
  const int w  = t >> 6;
  const int l  = t & 63;
  const int li = l & 15;
  const int g  = l >> 4;

  float kbv[4][4], vbv[4][4];
#pragma unroll
  for (int ot = 0; ot < 4; ++ot)
#pragma unroll
    for (int rg = 0; rg < 4; ++rg) {
      kbv[ot][rg] = kb[ot * 16 + g * 4 + rg];
      vbv[ot][rg] = vb[ot * 16 + g * 4 + rg];
    }

  bf16x8 ones;
#pragma unroll
  for (int j = 0; j < 8; ++j) ones[j] = (short)0x3F80;

  f32x4 accM[4];
#pragma unroll
  for (int ct = 0; ct < 4; ++ct) accM[ct] = (f32x4){0.f, 0.f, 0.f, 0.f};
  f32x4 accSk = (f32x4){0.f, 0.f, 0.f, 0.f};
  f32x4 accSv = (f32x4){0.f, 0.f, 0.f, 0.f};

  // staging addressing (fixed per thread)
  const int ch = t >> 2;
  const int ps = t & 3;
  const float* srcb = x + (size_t)ch * N_ + chunk * 1024 + ps * 16;
  unsigned short* xdst = &Xs[(ps * 16) * 72 + (ch ^ (ps << 4))];

  // prologue: prefetch iter 0
  float4 pA = ((const float4*)srcb)[0];
  float4 pB = ((const float4*)srcb)[1];
  float4 pC = ((const float4*)srcb)[2];
  float4 pD = ((const float4*)srcb)[3];

  for (int it = 0; it < 16; ++it) {
    // ---- write-late: stage prefetched x -> Xs (bf16)
    {
      float v[16] = {pA.x, pA.y, pA.z, pA.w, pB.x, pB.y, pB.z, pB.w,
                     pC.x, pC.y, pC.z, pC.w, pD.x, pD.y, pD.z, pD.w};
#pragma unroll
      for (int i = 0; i < 16; ++i) xdst[i * 72] = f2bf(v[i]);
    }
    // ---- issue-early: prefetch iter it+1 (flies across proj+matrix)
    if (it < 15) {
      const float* src = srcb + (it + 1) * 64;
      pA = ((const float4*)src)[0];
      pB = ((const float4*)src)[1];
      pC = ((const float4*)src)[2];
      pD = ((const float4*)src)[3];
    }
    __syncthreads();   // Xs visible; fences matrix(it-1) reads of Ks/Vs

    bf16x8 bx0 = *(const bf16x8*)&Xs[(w * 16 + li) * 72 + ((g * 8) ^ (w << 4))];
    bf16x8 bx1 = *(const bf16x8*)&Xs[(w * 16 + li) * 72 + ((32 + g * 8) ^ (w << 4))];

    f32x4 ka[4];
#pragma unroll
    for (int ot = 0; ot < 4; ++ot) {
      f32x4 a = (f32x4){0.f, 0.f, 0.f, 0.f};
      const bf16x8 w0 = *(const bf16x8*)(WKr + ((ot * 2 + 0) * 64 + l) * 8);
      const bf16x8 w1 = *(const bf16x8*)(WKr + ((ot * 2 + 1) * 64 + l) * 8);
      a = __builtin_amdgcn_mfma_f32_16x16x32_bf16(w0, bx0, a, 0, 0, 0);
      a = __builtin_amdgcn_mfma_f32_16x16x32_bf16(w1, bx1, a, 0, 0, 0);
      ka[ot] = a;
    }
    float ss = 0.f;
#pragma unroll
    for (int ot = 0; ot < 4; ++ot)
#pragma unroll
      for (int rg = 0; rg < 4; ++rg) {
        const float v2 = ka[ot][rg] + kbv[ot][rg];
        ka[ot][rg] = v2;
        ss += v2 * v2;
      }
    ss += __shfl_xor(ss, 16);
    ss += __shfl_xor(ss, 32);
    const float inv = rsqrtf(ss);
#pragma unroll
    for (int ot = 0; ot < 4; ++ot)
#pragma unroll
      for (int rg = 0; rg < 4; ++rg)
        Ks[(ot * 16 + g * 4 + rg) * 72 + w * 16 + li] = f2bf(ka[ot][rg] * inv);

#pragma unroll
    for (int ot = 0; ot < 4; ++ot) {
      f32x4 a = (f32x4){0.f, 0.f, 0.f, 0.f};
      const bf16x8 w0 = *(const bf16x8*)(WKr + 4096 + ((ot * 2 + 0) * 64 + l) * 8);
      const bf16x8 w1 = *(const bf16x8*)(WKr + 4096 + ((ot * 2 + 1) * 64 + l) * 8);
      a = __builtin_amdgcn_mfma_f32_16x16x32_bf16(w0, bx0, a, 0, 0, 0);
      a = __builtin_amdgcn_mfma_f32_16x16x32_bf16(w1, bx1, a, 0, 0, 0);
#pragma unroll
      for (int rg = 0; rg < 4; ++rg)
        Vs[(ot * 16 + g * 4 + rg) * 72 + w * 16 + li] = f2bf(a[rg] + vbv[ot][rg]);
    }
    __syncthreads();   // Ks/Vs visible for matrix

#pragma unroll
    for (int ks = 0; ks < 2; ++ks) {
      const int ko = ks * 32 + g * 8;
      const bf16x8 aK = *(const bf16x8*)&Ks[(w * 16 + li) * 72 + ko];
      const bf16x8 aV = *(const bf16x8*)&Vs[(w * 16 + li) * 72 + ko];
      accSk = __builtin_amdgcn_mfma_f32_16x16x32_bf16(aK, ones, accSk, 0, 0, 0);
      accSv = __builtin_amdgcn_mfma_f32_16x16x32_bf16(aV, ones, accSv, 0, 0, 0);
#pragma unroll
      for (int ct = 0; ct < 4; ++ct) {
        const bf16x8 bV = *(const bf16x8*)&Vs[(ct * 16 + li) * 72 + ko];
        accM[ct] = __builtin_amdgcn_mfma_f32_16x16x32_bf16(aK, bV, accM[ct], 0, 0, 0);
      }
    }
  }

  float* pb = partials + ((size_t)(r * B_ + b) * CHUNKS + chunk) * STATS;
#pragma unroll
  for (int ct = 0; ct < 4; ++ct)
#pragma unroll
    for (int rg = 0; rg < 4; ++rg)
      pb[(w * 16 + g * 4 + rg) * 64 + ct * 16 + li] = accM[ct][rg];
  if (li == 0) {
#pragma unroll
    for (int rg = 0; rg < 4; ++rg) {
      pb[4096 + w * 16 + g * 4 + rg] = accSk[rg];
      pb[4160 + w * 16 + g * 4 + rg] = accSv[rg];
    }
  }
}

// ================================================================
// Finalize: reduce partials, fold r_w in. (unchanged)
// ================================================================
__global__ void finalize_kernel(const float* __restrict__ partials,
                                const float* __restrict__ r1w,
                                const float* __restrict__ r2w,
                                float* __restrict__ derived)
{
  const int bb = blockIdx.x;
  const int r = bb >> 3;
  const float* rw = r ? r2w : r1w;
  __shared__ float mat[4096];
  __shared__ float ks[64], vs[64];
  const int t = threadIdx.x;
  const float* pb = partials + (size_t)bb * CHUNKS * STATS;
  for (int e = t; e < STATS; e += 256) {
    float s = 0.f;
    for (int j = 0; j < CHUNKS; ++j) s += pb[(size_t)j * STATS + e];
    if (e < 4096) mat[e] = s;
    else if (e < 4160) ks[e - 4096] = s;
    else vs[e - 4160] = s;
  }
  __syncthreads();
  float* der = derived + (size_t)bb * STATS;
  for (int e = t; e < 4096; e += 256) {
    const int o = e >> 6, m = e & 63;
    float s = 0.f;
    for (int c = 0; c < 64; ++c) s += rw[o * 64 + c] * mat[m * 64 + c];
    der[e] = s;
  }
  if (t < 64) {
    float s = 0.f;
    for (int c = 0; c < 64; ++c) s += rw[t * 64 + c] * vs[c];
    der[4096 + t] = s;
    der[4160 + t] = ks[t] + EPSF;
  }
}

// ================================================================
// Pass 2 (MFMA attn).
// ROUND-15: T14 prefetch on x staging — loads for iter it+1 issued
// right after the staging write, flying across the whole compute
// phase (proj + out-GEMM + stores). Barrier count unchanged (2).
// ================================================================
__global__ __launch_bounds__(256, 2) void attn_mfma_kernel(
    const float* __restrict__ t1, const float* __restrict__ t2,
    const float* __restrict__ q1b, const float* __restrict__ q2b,
    const float* __restrict__ r1b, const float* __restrict__ r2b,
    const float* __restrict__ derived,
    const unsigned short* __restrict__ QWA,
    const unsigned short* __restrict__ RMA,
    __hip_bfloat16* __restrict__ catH, __hip_bfloat16* __restrict__ catL)
{
  const int chunk = blockIdx.x;
  const int b = blockIdx.y;
  const int rbr = blockIdx.z;
  const float* x  = (rbr ? t2 : t1) + (size_t)b * C_ * N_;
  const float* qb = rbr ? q2b : q1b;
  const float* rb = rbr ? r2b : r1b;
  const int bb = rbr * B_ + b;
  const float* der = derived + (size_t)bb * STATS;
  const unsigned short* qwa = QWA + rbr * 8192;
  const unsigned short* rma = RMA + (size_t)bb * 8192;

  __shared__ unsigned short XsH[64 * 72];
  __shared__ unsigned short XsL[64 * 72];
  __shared__ unsigned short QsH[64 * 72];
  __shared__ unsigned short QsL[64 * 72];

  const int t  = threadIdx.x;
  const int w  = t >> 6;
  const int l  = t & 63;
  const int li = l & 15;
  const int g  = l >> 4;

  float qbv[16], ksev[16], rvsv[16], rbv[16];
#pragma unroll
  for (int ot = 0; ot < 4; ++ot)
#pragma unroll
    for (int rg = 0; rg < 4; ++rg) {
      const int row = ot * 16 + g * 4 + rg;
      qbv[ot * 4 + rg]  = qb[row];
      ksev[ot * 4 + rg] = der[4160 + row];
      rvsv[ot * 4 + rg] = der[4096 + row];
      rbv[ot * 4 + rg]  = rb[row];
    }

  // staging addressing (fixed per thread)
  const int ch = t >> 2;
  const int ps = t & 3;
  const float* srcb = x + (size_t)ch * N_ + chunk * 1024 + ps * 16;
  const int xcol = ch ^ (ps << 4);
  unsigned short* dH = &XsH[(ps * 16) * 72 + xcol];
  unsigned short* dL = &XsL[(ps * 16) * 72 + xcol];

  // prologue: prefetch iter 0
  float4 pA = ((const float4*)srcb)[0];
  float4 pB = ((const float4*)srcb)[1];
  float4 pC = ((const float4*)srcb)[2];
  float4 pD = ((const float4*)srcb)[3];

#pragma clang loop unroll(disable)
  for (int it = 0; it < 16; ++it) {
    const int px0 = chunk * 1024 + it * 64;
    __syncthreads();   // bar_pre: fences compute(it-1) reads of XsH/L
    // ---- write-late: stage prefetched x -> XsH/XsL (hi/lo bf16)
    {
      float v[16] = {pA.x, pA.y, pA.z, pA.w, pB.x, pB.y, pB.z, pB.w,
                     pC.x, pC.y, pC.z, pC.w, pD.x, pD.y, pD.z, pD.w};
#pragma unroll
      for (int i = 0; i < 16; ++i) {
        const unsigned short h = f2bf(v[i]);
        dH[i * 72] = h;
        dL[i * 72] = f2bf(v[i] - __uint_as_float((unsigned)h << 16));
      }
    }
    // ---- issue-early: prefetch iter it+1 (flies across compute)
    if (it < 15) {
      const float* src = srcb + (it + 1) * 64;
      pA = ((const float4*)src)[0];
      pB = ((const float4*)src)[1];
      pC = ((const float4*)src)[2];
      pD = ((const float4*)src)[3];
    }
    __syncthreads();   // bar_post: XsH/L visible

    const int rowb = (w * 16 + li) * 72;
    const bf16x8 bxh0 = *(const bf16x8*)&XsH[rowb + ((g * 8) ^ (w << 4))];
    const bf16x8 bxh1 = *(const bf16x8*)&XsH[rowb + ((32 + g * 8) ^ (w << 4))];
    const bf16x8 bxl0 = *(const bf16x8*)&XsL[rowb + ((g * 8) ^ (w << 4))];
    const bf16x8 bxl1 = *(const bf16x8*)&XsL[rowb + ((32 + g * 8) ^ (w << 4))];

    float q[16];
#pragma unroll
    for (int ot = 0; ot < 4; ++ot) {
      f32x4 a = (f32x4){0.f, 0.f, 0.f, 0.f};
      const bf16x8 wh0 = *(const bf16x8*)(qwa + ((0 * 4 + ot) * 2 + 0) * 512 + l * 8);
      const bf16x8 wh1 = *(const bf16x8*)(qwa + ((0 * 4 + ot) * 2 + 1) * 512 + l * 8);
      const bf16x8 wl0 = *(const bf16x8*)(qwa + ((1 * 4 + ot) * 2 + 0) * 512 + l * 8);
      const bf16x8 wl1 = *(const bf16x8*)(qwa + ((1 * 4 + ot) * 2 + 1) * 512 + l * 8);
      a = __builtin_amdgcn_mfma_f32_16x16x32_bf16(wh0, bxh0, a, 0, 0, 0);
      a = __builtin_amdgcn_mfma_f32_16x16x32_bf16(wh1, bxh1, a, 0, 0, 0);
      a = __builtin_amdgcn_mfma_f32_16x16x32_bf16(wh0, bxl0, a, 0, 0, 0);
      a = __builtin_amdgcn_mfma_f32_16x16x32_bf16(wh1, bxl1, a, 0, 0, 0);
      a = __builtin_amdgcn_mfma_f32_16x16x32_bf16(wl0, bxh0, a, 0, 0, 0);
      a = __builtin_amdgcn_mfma_f32_16x16x32_bf16(wl1, bxh1, a, 0, 0, 0);
#pragma unroll
      for (int rg = 0; rg < 4; ++rg) q[ot * 4 + rg] = a[rg] + qbv[ot * 4 + rg];
    }

    float ss = 0.f, d = 0.f;
#pragma unroll
    for (int i = 0; i < 16; ++i) { ss += q[i] * q[i]; d += q[i] * ksev[i]; }
    ss += __shfl_xor(ss, 16);  ss += __shfl_xor(ss, 32);
    d  += __shfl_xor(d, 16);   d  += __shfl_xor(d, 32);
    const float inv = rsqrtf(ss);
    const float rden = 1.0f / (65536.0f + inv * d);
    const float f1 = rden * inv;

#pragma unroll
    for (int ot = 0; ot < 4; ++ot) {
      unsigned h0, h1, h2, h3, l0, l1, l2, l3;
      {
        const float v0 = q[ot * 4 + 0], v1 = q[ot * 4 + 1];
        const float v2 = q[ot * 4 + 2], v3 = q[ot * 4 + 3];
        h0 = f2bf(v0); l0 = f2bf(v0 - __uint_as_float(h0 << 16));
        h1 = f2bf(v1); l1 = f2bf(v1 - __uint_as_float(h1 << 16));
        h2 = f2bf(v2); l2 = f2bf(v2 - __uint_as_float(h2 << 16));
        h3 = f2bf(v3); l3 = f2bf(v3 - __uint_as_float(h3 << 16));
      }
      const int off = (w * 16 + li) * 72 + ot * 16 + g * 4;
      *(uint2*)&QsH[off] = make_uint2(h0 | (h1 << 16), h2 | (h3 << 16));
      *(uint2*)&QsL[off] = make_uint2(l0 | (l1 << 16), l2 | (l3 << 16));
    }

    const bf16x8 bqh0 = *(const bf16x8*)&QsH[rowb + g * 8];
    const bf16x8 bqh1 = *(const bf16x8*)&QsH[rowb + 32 + g * 8];
    const bf16x8 bql0 = *(const bf16x8*)&QsL[rowb + g * 8];
    const bf16x8 bql1 = *(const bf16x8*)&QsL[rowb + 32 + g * 8];

#pragma unroll
    for (int ot = 0; ot < 4; ++ot) {
      f32x4 a = (f32x4){0.f, 0.f, 0.f, 0.f};
      const bf16x8 rh0 = *(const bf16x8*)(rma + ((0 * 4 + ot) * 2 + 0) * 512 + l * 8);
      const bf16x8 rh1 = *(const bf16x8*)(rma + ((0 * 4 + ot) * 2 + 1) * 512 + l * 8);
      const bf16x8 rl0 = *(const bf16x8*)(rma + ((1 * 4 + ot) * 2 + 0) * 512 + l * 8);
      const bf16x8 rl1 = *(const bf16x8*)(rma + ((1 * 4 + ot) * 2 + 1) * 512 + l * 8);
      a = __builtin_amdgcn_mfma_f32_16x16x32_bf16(rh0, bqh0, a, 0, 0, 0);
      a = __builtin_amdgcn_mfma_f32_16x16x32_bf16(rh1, bqh1, a, 0, 0, 0);
      a = __builtin_amdgcn_mfma_f32_16x16x32_bf16(rh0, bql0, a, 0, 0, 0);
      a = __builtin_amdgcn_mfma_f32_16x16x32_bf16(rh1, bql1, a, 0, 0, 0);
      a = __builtin_amdgcn_mfma_f32_16x16x32_bf16(rl0, bqh0, a, 0, 0, 0);
      a = __builtin_amdgcn_mfma_f32_16x16x32_bf16(rl1, bqh1, a, 0, 0, 0);

      unsigned h0, h1, h2, h3, l0, l1, l2, l3;
      {
        const float a0 = f1 * a[0] + rden * rvsv[ot * 4 + 0] + rbv[ot * 4 + 0];
        const float a1 = f1 * a[1] + rden * rvsv[ot * 4 + 1] + rbv[ot * 4 + 1];
        const float a2 = f1 * a[2] + rden * rvsv[ot * 4 + 2] + rbv[ot * 4 + 2];
        const float a3 = f1 * a[3] + rden * rvsv[ot * 4 + 3] + rbv[ot * 4 + 3];
        h0 = f2bf(a0); l0 = f2bf(a0 - __uint_as_float(h0 << 16));
        h1 = f2bf(a1); l1 = f2bf(a1 - __uint_as_float(h1 << 16));
        h2 = f2bf(a2); l2 = f2bf(a2 - __uint_as_float(h2 << 16));
        h3 = f2bf(a3); l3 = f2bf(a3 - __uint_as_float(h3 << 16));
      }
      const size_t base =
          (((size_t)(b * 8 + rbr * 4 + ot)) * N_ + (px0 + w * 16 + li)) * 16 + g * 4;
      *(uint2*)(catH + base) = make_uint2(h0 | (h1 << 16), h2 | (h3 << 16));
      *(uint2*)(catL + base) = make_uint2(l0 | (l1 << 16), l2 | (l3 << 16));
    }
  }
}

// ================================================================
// prep_wa: conv weights -> A-frag order, split bf16 hi/lo. (unchanged)
// ================================================================
__global__ void prep_wa_kernel(const float* __restrict__ cw,
                               __hip_bfloat16* __restrict__ WA) {
  const int e = blockIdx.x * 256 + threadIdx.x;
  if (e >= 8 * 5 * 2 * 4 * 512) return;
  const int j    = e & 7;
  const int lane = (e >> 3) & 63;
  const int f    = e >> 9;
  const int ot   = f & 3;
  const int v    = (f >> 2) & 1;
  const int s    = (f >> 3) % 5;
  const int c    = (f >> 3) / 5;
  const int o    = ot * 16 + (lane & 15);
  const int g    = lane >> 4;
  const int tap  = 2 * s + (g >> 1);
  float val = 0.f;
  if (tap <= 8) {
    const int ci = c * 16 + (g & 1) * 8 + j;
    val = cw[(size_t)(o * 128 + ci) * 9 + tap];
  }
  __hip_bfloat16 h = __float2bfloat16(val);
  if (v) h = __float2bfloat16(val - __bfloat162float(h));
  WA[e] = h;
}

// ================================================================
// Pass 3: 3x3 conv via MFMA implicit GEMM, split-bf16, T14 pipeline,
// LDS dbuf, (row, ot-half) wave split. (unchanged from round 14 —
// plateaued at ~229 us in the 2-phase structure)
// ================================================================
__global__ __launch_bounds__(512, 4) void conv_mfma_kernel(
    const __hip_bfloat16* __restrict__ catH,
    const __hip_bfloat16* __restrict__ catL,
    const __hip_bfloat16* __restrict__ WA,
    const float* __restrict__ cb,
    float* __restrict__ out)
{
  __shared__ __hip_bfloat16 XsH[2][6 * 68 * 24];
  __shared__ __hip_bfloat16 XsL[2][6 * 68 * 24];

  const int t  = threadIdx.x;
  const int v  = t >> 6;        // wave id 0..7
  const int wr = v >> 1;        // output row 0..3
  const int oh = v & 1;         // ot-half: ots {2oh, 2oh+1}
  const int l  = t & 63;
  const int li = l & 15;
  const int g  = l >> 4;
  const int x0 = blockIdx.x * 64;
  const int y0 = blockIdx.y * 4;
  const int b  = blockIdx.z;

  const bool hasA = (t < 396);
  const int rA = t / 66, cA = t - rA * 66;
  const int gyA = y0 + rA - 1, gxA = x0 + cA - 1;
  const bool okA = hasA && ((unsigned)gyA < 256u) && ((unsigned)gxA < 256u);
  const size_t offA = ((size_t)(gyA * HW_ + gxA)) * 16;
  const int leA = (rA * 68 + cA) * 24;
  const uint4 Z = make_uint4(0u, 0u, 0u, 0u);

  uint4 Ah0, Ah1, Al0, Al1;

  f32x4 acc[2][4];
#pragma unroll
  for (int i = 0; i < 2; ++i)
#pragma unroll
    for (int k = 0; k < 4; ++k) acc[i][k] = (f32x4){0.f, 0.f, 0.f, 0.f};

  {
    const size_t chb = ((size_t)(b * 8 + 0)) * N_ * 16;
    Ah0 = Ah1 = Al0 = Al1 = Z;
    if (okA) {
      const uint4* ph = (const uint4*)(catH + chb + offA);
      Ah0 = ph[0]; Ah1 = ph[1];
      const uint4* pl = (const uint4*)(catL + chb + offA);
      Al0 = pl[0]; Al1 = pl[1];
    }
  }

  for (int c = 0; c < 8; ++c) {
    const int cur = c & 1;
    if (hasA) {
      *(uint4*)(&XsH[cur][leA]) = Ah0; *(uint4*)(&XsH[cur][leA + 8]) = Ah1;
      *(uint4*)(&XsL[cur][leA]) = Al0; *(uint4*)(&XsL[cur][leA + 8]) = Al1;
    }
    if (c < 7) {
      const size_t chb = ((size_t)(b * 8 + c + 1)) * N_ * 16;
      Ah0 = Ah1 = Al0 = Al1 = Z;
      if (okA) {
        const uint4* ph = (const uint4*)(catH + chb + offA);
        Ah0 = ph[0]; Ah1 = ph[1];
        const uint4* pl = (const uint4*)(catL + chb + offA);
        Al0 = pl[0]; Al1 = pl[1];
      }
    }
    __syncthreads();

    const __hip_bfloat16* xh = XsH[cur];
    const __hip_bfloat16* xl = XsL[cur];
    const __hip_bfloat16* wa_c = WA + (size_t)c * 20480;
#pragma unroll
    for (int s = 0; s < 5; ++s) {
      const __hip_bfloat16* wa_s = wa_c + s * 4096 + l * 8;
      bf16x8 aH[2], aL[2];
#pragma unroll
      for (int oi = 0; oi < 2; ++oi) {
        aH[oi] = *(const bf16x8*)(wa_s + (oh * 2 + oi) * 512);
        aL[oi] = *(const bf16x8*)(wa_s + 2048 + (oh * 2 + oi) * 512);
      }

      int tap = 2 * s + (g >> 1);
      if (tap > 8) tap = 0;
      const int ky = tap / 3;
      const int kx = tap - ky * 3;
      const int e0 = ((wr + ky) * 68 + li + kx) * 24 + (g & 1) * 8;

#pragma unroll
      for (int pt = 0; pt < 4; ++pt) {
        const bf16x8 bH = *(const bf16x8*)(&xh[e0 + pt * 384]);
        const bf16x8 bL = *(const bf16x8*)(&xl[e0 + pt * 384]);
#pragma unroll
        for (int oi = 0; oi < 2; ++oi) {
          acc[oi][pt] = __builtin_amdgcn_mfma_f32_16x16x32_bf16(
              aH[oi], bH, acc[oi][pt], 0, 0, 0);
          acc[oi][pt] = __builtin_amdgcn_mfma_f32_16x16x32_bf16(
              aH[oi], bL, acc[oi][pt], 0, 0, 0);
          acc[oi][pt] = __builtin_amdgcn_mfma_f32_16x16x32_bf16(
              aL[oi], bH, acc[oi][pt], 0, 0, 0);
        }
      }
    }
  }

#pragma unroll
  for (int oi = 0; oi < 2; ++oi)
#pragma unroll
    for (int r = 0; r < 4; ++r) {
      const int o = (oh * 2 + oi) * 16 + g * 4 + r;
      const float bv = cb[o];
      float* orow = out + ((size_t)b * 64 + o) * N_ + (size_t)(y0 + wr) * HW_ + x0 + li;
#pragma unroll
      for (int pt = 0; pt < 4; ++pt)
        orow[pt * 16] = acc[oi][pt][r] + bv;
    }
}

// ================================================================
extern "C" void kernel_launch(void* const* d_in, const int* in_sizes, int n_in,
                              void* d_out, int out_size, void* d_ws, size_t ws_size,
                              hipStream_t stream) {
  const float* t1  = (const float*)d_in[0];
  const float* t2  = (const float*)d_in[1];
  const float* q1w = (const float*)d_in[2];
  const float* q1b = (const float*)d_in[3];
  const float* k1w = (const float*)d_in[4];
  const float* k1b = (const float*)d_in[5];
  const float* v1w = (const float*)d_in[6];
  const float* v1b = (const float*)d_in[7];
  const float* r1w = (const float*)d_in[8];
  const float* r1b = (const float*)d_in[9];
  const float* q2w = (const float*)d_in[10];
  const float* q2b = (const float*)d_in[11];
  const float* k2w = (const float*)d_in[12];
  const float* k2b = (const float*)d_in[13];
  const float* v2w = (const float*)d_in[14];
  const float* v2b = (const float*)d_in[15];
  const float* r2w = (const float*)d_in[16];
  const float* r2b = (const float*)d_in[17];
  const float* cw  = (const float*)d_in[18];
  const float* cbp = (const float*)d_in[19];
  float* out = (float*)d_out;

  // ws: [catH 128MB][catL 128MB][partials 16.5MB][derived 264KB]
  // Aliases inside the dead-after-finalize partials region:
  //   WA at +0 (320KB), RMA at +1MB (256KB), QWA at +2MB (32KB).
  // WK (stats weights) aliases catH (dead until attn runs).
  char* ws = (char*)d_ws;
  const size_t catB  = (size_t)B_ * 8 * N_ * 16 * 2;     // 128 MB each
  const size_t partB = (size_t)16 * CHUNKS * STATS * sizeof(float);
  __hip_bfloat16* catHp = (__hip_bfloat16*)ws;
  __hip_bfloat16* catLp = (__hip_bfloat16*)(ws + catB);
  float* part = (float*)(ws + 2 * catB);
  float* der  = (float*)(ws + 2 * catB + partB);
  __hip_bfloat16* WA   = (__hip_bfloat16*)part;                         // alias
  unsigned short* RMAp = (unsigned short*)(ws + 2 * catB + (1u << 20)); // alias
  unsigned short* QWAp = (unsigned short*)(ws + 2 * catB + (2u << 20)); // alias
  unsigned short* WKp  = (unsigned short*)ws;                           // alias (catH)

  prep_proj_kernel<<<dim3(64), 256, 0, stream>>>(k1w, v1w, k2w, v2w, WKp);
  stats_mfma_kernel<<<dim3(CHUNKS, B_, 2), 256, 0, stream>>>(
      t1, t2, k1b, v1b, k2b, v2b, WKp, part);
  finalize_kernel<<<dim3(16), 256, 0, stream>>>(part, r1w, r2w, der);
  qw_prep_kernel<<<dim3(64), 256, 0, stream>>>(q1w, q2w, QWAp);
  rm_prep_kernel<<<dim3(512), 256, 0, stream>>>(der, RMAp);
  prep_wa_kernel<<<dim3(640), 256, 0, stream>>>(cw, WA);
  attn_mfma_kernel<<<dim3(CHUNKS, B_, 2), 256, 0, stream>>>(
      t1, t2, q1b, q2b, r1b, r2b, der, QWAp, RMAp, catHp, catLp);
  conv_mfma_kernel<<<dim3(4, 64, B_), 512, 0, stream>>>(
      catHp, catLp, WA, cbp, out);
}

// Round 16
// 498.418 us; speedup vs baseline: 1.0974x; 1.0974x over previous
//
#include <hip/hip_runtime.h>
#include <hip/hip_bf16.h>

// Problem constants (fixed by setup_inputs)
constexpr int B_ = 8;
constexpr int C_ = 64;      // input channels = KC = VC = 64
constexpr int N_ = 65536;   // H*W = 256*256
constexpr int HW_ = 256;
constexpr float EPSF = 1e-6f;
constexpr int STATS = 4224; // 4096 matrix + 64 ksum + 64 vsum
constexpr int CHUNKS = 64;  // stats blocks per (branch,batch)

typedef __attribute__((ext_vector_type(8))) short bf16x8;
typedef __attribute__((ext_vector_type(4))) float f32x4;

// RNE fp32 -> bf16 bits, pure bit arithmetic (no address-taken locals)
__device__ __forceinline__ unsigned short f2bf(float f) {
  const unsigned u = __float_as_uint(f);
  return (unsigned short)((u + 0x7fffu + ((u >> 16) & 1u)) >> 16);
}

// Cheap TRUNCATION hi/lo split (round-16): the pair (hi,lo) represents
// v to <= 2^-16|v| regardless of hi's rounding (residual subtraction is
// exact). 4 VALU ops vs ~11 for the RNE pair. Returned by value (no
// address-taken locals -> no scratch).
__device__ __forceinline__ uint2 split2(float v) {
  const unsigned u = __float_as_uint(v);
  const float lo = v - __uint_as_float(u & 0xffff0000u);
  return make_uint2(u >> 16, __float_as_uint(lo) >> 16);
}

// ================================================================
// prep_proj: K/V projection weights -> MFMA A-fragment order, bf16.
// WK[r(2)][kv(2)][ot(4)][ks(2)][lane(64)][j(8)]  (unchanged)
// ================================================================
__global__ void prep_proj_kernel(const float* __restrict__ k1w,
                                 const float* __restrict__ v1w,
                                 const float* __restrict__ k2w,
                                 const float* __restrict__ v2w,
                                 unsigned short* __restrict__ WK) {
  const int e = blockIdx.x * 256 + threadIdx.x;   // 16384 total
  if (e >= 16384) return;
  const int j    = e & 7;
  const int lane = (e >> 3) & 63;
  const int ks   = (e >> 9) & 1;
  const int ot   = (e >> 10) & 3;
  const int kv   = (e >> 12) & 1;
  const int r    = (e >> 13) & 1;
  const int m    = ot * 16 + (lane & 15);
  const int ch   = ks * 32 + ((lane >> 4) & 3) * 8 + j;
  const float* w = r ? (kv ? v2w : k2w) : (kv ? v1w : k1w);
  WK[e] = f2bf(w[m * 64 + ch]);
}

// ================================================================
// qw_prep: Q projection weights -> A-frag order, bf16 HI/LO planes.
// ================================================================
__global__ void qw_prep_kernel(const float* __restrict__ q1w,
                               const float* __restrict__ q2w,
                               unsigned short* __restrict__ QWA) {
  const int e = blockIdx.x * 256 + threadIdx.x;
  if (e >= 16384) return;
  const int j    = e & 7;
  const int lane = (e >> 3) & 63;
  const int ks   = (e >> 9) & 1;
  const int ot   = (e >> 10) & 3;
  const int v    = (e >> 12) & 1;
  const int r    = (e >> 13) & 1;
  const int m    = ot * 16 + (lane & 15);
  const int ch   = ks * 32 + ((lane >> 4) & 3) * 8 + j;
  const float val = (r ? q2w : q1w)[m * 64 + ch];
  unsigned short h = f2bf(val);
  if (v) h = f2bf(val - __uint_as_float((unsigned)h << 16));
  QWA[e] = h;
}

// ================================================================
// rm_prep: rm (= derived[bb][o*64+m]) -> A-frag order bf16 HI/LO.
// ================================================================
__global__ void rm_prep_kernel(const float* __restrict__ derived,
                               unsigned short* __restrict__ RMA) {
  const int e = blockIdx.x * 256 + threadIdx.x;   // 131072 total
  if (e >= 131072) return;
  const int j    = e & 7;
  const int lane = (e >> 3) & 63;
  const int ks   = (e >> 9) & 1;
  const int ot   = (e >> 10) & 3;
  const int v    = (e >> 12) & 1;
  const int bb   = e >> 13;
  const int o    = ot * 16 + (lane & 15);
  const int m    = ks * 32 + ((lane >> 4) & 3) * 8 + j;
  const float val = derived[(size_t)bb * STATS + o * 64 + m];
  unsigned short h = f2bf(val);
  if (v) h = f2bf(val - __uint_as_float((unsigned)h << 16));
  RMA[e] = h;
}

// ================================================================
// Pass 1 (MFMA stats) — ROUND-16: reverted to the round-14 form
// (round 15's prefetch + barrier removal regressed; stats is not
// load-latency-bound).
// ================================================================
__global__ __launch_bounds__(256, 2) void stats_mfma_kernel(
    const float* __restrict__ t1, const float* __restrict__ t2,
    const float* __restrict__ k1b, const float* __restrict__ v1b,
    const float* __restrict__ k2b, const float* __restrict__ v2b,
    const unsigned short* __restrict__ WK,
    float* __restrict__ partials)
{
  const int chunk = blockIdx.x;
  const int b = blockIdx.y;
  const int r = blockIdx.z;
  const float* x  = (r ? t2 : t1) + (size_t)b * C_ * N_;
  const float* kb = r ? k2b : k1b;
  const float* vb = r ? v2b : v1b;
  const unsigned short* WKr = WK + r * 8192;

  __shared__ unsigned short Xs[64 * 72];
  __shared__ unsigned short Ks[64 * 72];
  __shared__ unsigned short Vs[64 * 72];

  const int t  = threadIdx.x;
  const int w  = t >> 6;
  const int l  = t & 63;
  const int li = l & 15;
  const int g  = l >> 4;

  float kbv[4][4], vbv[4][4];
#pragma unroll
  for (int ot = 0; ot < 4; ++ot)
#pragma unroll
    for (int rg = 0; rg < 4; ++rg) {
      kbv[ot][rg] = kb[ot * 16 + g * 4 + rg];
      vbv[ot][rg] = vb[ot * 16 + g * 4 + rg];
    }

  bf16x8 ones;
#pragma unroll
  for (int j = 0; j < 8; ++j) ones[j] = (short)0x3F80;

  f32x4 accM[4];
#pragma unroll
  for (int ct = 0; ct < 4; ++ct) accM[ct] = (f32x4){0.f, 0.f, 0.f, 0.f};
  f32x4 accSk = (f32x4){0.f, 0.f, 0.f, 0.f};
  f32x4 accSv = (f32x4){0.f, 0.f, 0.f, 0.f};

  for (int it = 0; it < 16; ++it) {
    const int px0 = chunk * 1024 + it * 64;
    __syncthreads();
    {
      const int ch = t >> 2;
      const int ps = t & 3;
      const float* src = x + (size_t)ch * N_ + px0 + ps * 16;
      const float4 f0 = ((const float4*)src)[0];
      const float4 f1 = ((const float4*)src)[1];
      const float4 f2 = ((const float4*)src)[2];
      const float4 f3 = ((const float4*)src)[3];
      float v[16] = {f0.x, f0.y, f0.z, f0.w, f1.x, f1.y, f1.z, f1.w,
                     f2.x, f2.y, f2.z, f2.w, f3.x, f3.y, f3.z, f3.w};
      unsigned short* dst = &Xs[(ps * 16) * 72 + (ch ^ (ps << 4))];
#pragma unroll
      for (int i = 0; i < 16; ++i) dst[i * 72] = f2bf(v[i]);
    }
    __syncthreads();

    bf16x8 bx0 = *(const bf16x8*)&Xs[(w * 16 + li) * 72 + ((g * 8) ^ (w << 4))];
    bf16x8 bx1 = *(const bf16x8*)&Xs[(w * 16 + li) * 72 + ((32 + g * 8) ^ (w << 4))];

    f32x4 ka[4];
#pragma unroll
    for (int ot = 0; ot < 4; ++ot) {
      f32x4 a = (f32x4){0.f, 0.f, 0.f, 0.f};
      const bf16x8 w0 = *(const bf16x8*)(WKr + ((ot * 2 + 0) * 64 + l) * 8);
      const bf16x8 w1 = *(const bf16x8*)(WKr + ((ot * 2 + 1) * 64 + l) * 8);
      a = __builtin_amdgcn_mfma_f32_16x16x32_bf16(w0, bx0, a, 0, 0, 0);
      a = __builtin_amdgcn_mfma_f32_16x16x32_bf16(w1, bx1, a, 0, 0, 0);
      ka[ot] = a;
    }
    float ss = 0.f;
#pragma unroll
    for (int ot = 0; ot < 4; ++ot)
#pragma unroll
      for (int rg = 0; rg < 4; ++rg) {
        const float v2 = ka[ot][rg] + kbv[ot][rg];
        ka[ot][rg] = v2;
        ss += v2 * v2;
      }
    ss += __shfl_xor(ss, 16);
    ss += __shfl_xor(ss, 32);
    const float inv = rsqrtf(ss);
#pragma unroll
    for (int ot = 0; ot < 4; ++ot)
#pragma unroll
      for (int rg = 0; rg < 4; ++rg)
        Ks[(ot * 16 + g * 4 + rg) * 72 + w * 16 + li] = f2bf(ka[ot][rg] * inv);

#pragma unroll
    for (int ot = 0; ot < 4; ++ot) {
      f32x4 a = (f32x4){0.f, 0.f, 0.f, 0.f};
      const bf16x8 w0 = *(const bf16x8*)(WKr + 4096 + ((ot * 2 + 0) * 64 + l) * 8);
      const bf16x8 w1 = *(const bf16x8*)(WKr + 4096 + ((ot * 2 + 1) * 64 + l) * 8);
      a = __builtin_amdgcn_mfma_f32_16x16x32_bf16(w0, bx0, a, 0, 0, 0);
      a = __builtin_amdgcn_mfma_f32_16x16x32_bf16(w1, bx1, a, 0, 0, 0);
#pragma unroll
      for (int rg = 0; rg < 4; ++rg)
        Vs[(ot * 16 + g * 4 + rg) * 72 + w * 16 + li] = f2bf(a[rg] + vbv[ot][rg]);
    }
    __syncthreads();

#pragma unroll
    for (int ks = 0; ks < 2; ++ks) {
      const int ko = ks * 32 + g * 8;
      const bf16x8 aK = *(const bf16x8*)&Ks[(w * 16 + li) * 72 + ko];
      const bf16x8 aV = *(const bf16x8*)&Vs[(w * 16 + li) * 72 + ko];
      accSk = __builtin_amdgcn_mfma_f32_16x16x32_bf16(aK, ones, accSk, 0, 0, 0);
      accSv = __builtin_amdgcn_mfma_f32_16x16x32_bf16(aV, ones, accSv, 0, 0, 0);
#pragma unroll
      for (int ct = 0; ct < 4; ++ct) {
        const bf16x8 bV = *(const bf16x8*)&Vs[(ct * 16 + li) * 72 + ko];
        accM[ct] = __builtin_amdgcn_mfma_f32_16x16x32_bf16(aK, bV, accM[ct], 0, 0, 0);
      }
    }
  }

  float* pb = partials + ((size_t)(r * B_ + b) * CHUNKS + chunk) * STATS;
#pragma unroll
  for (int ct = 0; ct < 4; ++ct)
#pragma unroll
    for (int rg = 0; rg < 4; ++rg)
      pb[(w * 16 + g * 4 + rg) * 64 + ct * 16 + li] = accM[ct][rg];
  if (li == 0) {
#pragma unroll
    for (int rg = 0; rg < 4; ++rg) {
      pb[4096 + w * 16 + g * 4 + rg] = accSk[rg];
      pb[4160 + w * 16 + g * 4 + rg] = accSv[rg];
    }
  }
}

// ================================================================
// Finalize: reduce partials, fold r_w in. (unchanged)
// ================================================================
__global__ void finalize_kernel(const float* __restrict__ partials,
                                const float* __restrict__ r1w,
                                const float* __restrict__ r2w,
                                float* __restrict__ derived)
{
  const int bb = blockIdx.x;
  const int r = bb >> 3;
  const float* rw = r ? r2w : r1w;
  __shared__ float mat[4096];
  __shared__ float ks[64], vs[64];
  const int t = threadIdx.x;
  const float* pb = partials + (size_t)bb * CHUNKS * STATS;
  for (int e = t; e < STATS; e += 256) {
    float s = 0.f;
    for (int j = 0; j < CHUNKS; ++j) s += pb[(size_t)j * STATS + e];
    if (e < 4096) mat[e] = s;
    else if (e < 4160) ks[e - 4096] = s;
    else vs[e - 4160] = s;
  }
  __syncthreads();
  float* der = derived + (size_t)bb * STATS;
  for (int e = t; e < 4096; e += 256) {
    const int o = e >> 6, m = e & 63;
    float s = 0.f;
    for (int c = 0; c < 64; ++c) s += rw[o * 64 + c] * mat[m * 64 + c];
    der[e] = s;
  }
  if (t < 64) {
    float s = 0.f;
    for (int c = 0; c < 64; ++c) s += rw[t * 64 + c] * vs[c];
    der[4096 + t] = s;
    der[4160 + t] = ks[t] + EPSF;
  }
}

// ================================================================
// Pass 2 (MFMA attn) — ROUND-16: reverted to round-8 structure
// (round 15's prefetch regressed — attn is VALU-bound, not
// load-bound). NEW: all hi/lo splits use the 4-op TRUNCATION split
// (split2) instead of the ~11-op RNE pair: x staging, q-split, and
// epilogue. ~290 fewer VALU ops per thread-iter.
// ================================================================
__global__ __launch_bounds__(256, 2) void attn_mfma_kernel(
    const float* __restrict__ t1, const float* __restrict__ t2,
    const float* __restrict__ q1b, const float* __restrict__ q2b,
    const float* __restrict__ r1b, const float* __restrict__ r2b,
    const float* __restrict__ derived,
    const unsigned short* __restrict__ QWA,
    const unsigned short* __restrict__ RMA,
    __hip_bfloat16* __restrict__ catH, __hip_bfloat16* __restrict__ catL)
{
  const int chunk = blockIdx.x;
  const int b = blockIdx.y;
  const int rbr = blockIdx.z;
  const float* x  = (rbr ? t2 : t1) + (size_t)b * C_ * N_;
  const float* qb = rbr ? q2b : q1b;
  const float* rb = rbr ? r2b : r1b;
  const int bb = rbr * B_ + b;
  const float* der = derived + (size_t)bb * STATS;
  const unsigned short* qwa = QWA + rbr * 8192;
  const unsigned short* rma = RMA + (size_t)bb * 8192;

  __shared__ unsigned short XsH[64 * 72];
  __shared__ unsigned short XsL[64 * 72];
  __shared__ unsigned short QsH[64 * 72];
  __shared__ unsigned short QsL[64 * 72];

  const int t  = threadIdx.x;
  const int w  = t >> 6;
  const int l  = t & 63;
  const int li = l & 15;
  const int g  = l >> 4;

  float qbv[16], ksev[16], rvsv[16], rbv[16];
#pragma unroll
  for (int ot = 0; ot < 4; ++ot)
#pragma unroll
    for (int rg = 0; rg < 4; ++rg) {
      const int row = ot * 16 + g * 4 + rg;
      qbv[ot * 4 + rg]  = qb[row];
      ksev[ot * 4 + rg] = der[4160 + row];
      rvsv[ot * 4 + rg] = der[4096 + row];
      rbv[ot * 4 + rg]  = rb[row];
    }

#pragma clang loop unroll(disable)
  for (int it = 0; it < 16; ++it) {
    const int px0 = chunk * 1024 + it * 64;
    __syncthreads();
    {
      const int ch = t >> 2;
      const int ps = t & 3;
      const float* src = x + (size_t)ch * N_ + px0 + ps * 16;
      const float4 f0 = ((const float4*)src)[0];
      const float4 f1v = ((const float4*)src)[1];
      const float4 f2v = ((const float4*)src)[2];
      const float4 f3v = ((const float4*)src)[3];
      float v[16] = {f0.x, f0.y, f0.z, f0.w, f1v.x, f1v.y, f1v.z, f1v.w,
                     f2v.x, f2v.y, f2v.z, f2v.w, f3v.x, f3v.y, f3v.z, f3v.w};
      const int col = ch ^ (ps << 4);
      unsigned short* dH = &XsH[(ps * 16) * 72 + col];
      unsigned short* dL = &XsL[(ps * 16) * 72 + col];
#pragma unroll
      for (int i = 0; i < 16; ++i) {
        const uint2 hl = split2(v[i]);
        dH[i * 72] = (unsigned short)hl.x;
        dL[i * 72] = (unsigned short)hl.y;
      }
    }
    __syncthreads();

    const int rowb = (w * 16 + li) * 72;
    const bf16x8 bxh0 = *(const bf16x8*)&XsH[rowb + ((g * 8) ^ (w << 4))];
    const bf16x8 bxh1 = *(const bf16x8*)&XsH[rowb + ((32 + g * 8) ^ (w << 4))];
    const bf16x8 bxl0 = *(const bf16x8*)&XsL[rowb + ((g * 8) ^ (w << 4))];
    const bf16x8 bxl1 = *(const bf16x8*)&XsL[rowb + ((32 + g * 8) ^ (w << 4))];

    float q[16];
#pragma unroll
    for (int ot = 0; ot < 4; ++ot) {
      f32x4 a = (f32x4){0.f, 0.f, 0.f, 0.f};
      const bf16x8 wh0 = *(const bf16x8*)(qwa + ((0 * 4 + ot) * 2 + 0) * 512 + l * 8);
      const bf16x8 wh1 = *(const bf16x8*)(qwa + ((0 * 4 + ot) * 2 + 1) * 512 + l * 8);
      const bf16x8 wl0 = *(const bf16x8*)(qwa + ((1 * 4 + ot) * 2 + 0) * 512 + l * 8);
      const bf16x8 wl1 = *(const bf16x8*)(qwa + ((1 * 4 + ot) * 2 + 1) * 512 + l * 8);
      a = __builtin_amdgcn_mfma_f32_16x16x32_bf16(wh0, bxh0, a, 0, 0, 0);
      a = __builtin_amdgcn_mfma_f32_16x16x32_bf16(wh1, bxh1, a, 0, 0, 0);
      a = __builtin_amdgcn_mfma_f32_16x16x32_bf16(wh0, bxl0, a, 0, 0, 0);
      a = __builtin_amdgcn_mfma_f32_16x16x32_bf16(wh1, bxl1, a, 0, 0, 0);
      a = __builtin_amdgcn_mfma_f32_16x16x32_bf16(wl0, bxh0, a, 0, 0, 0);
      a = __builtin_amdgcn_mfma_f32_16x16x32_bf16(wl1, bxh1, a, 0, 0, 0);
#pragma unroll
      for (int rg = 0; rg < 4; ++rg) q[ot * 4 + rg] = a[rg] + qbv[ot * 4 + rg];
    }

    float ss = 0.f, d = 0.f;
#pragma unroll
    for (int i = 0; i < 16; ++i) { ss += q[i] * q[i]; d += q[i] * ksev[i]; }
    ss += __shfl_xor(ss, 16);  ss += __shfl_xor(ss, 32);
    d  += __shfl_xor(d, 16);   d  += __shfl_xor(d, 32);
    const float inv = rsqrtf(ss);
    const float rden = 1.0f / (65536.0f + inv * d);
    const float f1 = rden * inv;

#pragma unroll
    for (int ot = 0; ot < 4; ++ot) {
      const uint2 s0 = split2(q[ot * 4 + 0]);
      const uint2 s1 = split2(q[ot * 4 + 1]);
      const uint2 s2 = split2(q[ot * 4 + 2]);
      const uint2 s3 = split2(q[ot * 4 + 3]);
      const int off = (w * 16 + li) * 72 + ot * 16 + g * 4;
      *(uint2*)&QsH[off] = make_uint2(s0.x | (s1.x << 16), s2.x | (s3.x << 16));
      *(uint2*)&QsL[off] = make_uint2(s0.y | (s1.y << 16), s2.y | (s3.y << 16));
    }

    const bf16x8 bqh0 = *(const bf16x8*)&QsH[rowb + g * 8];
    const bf16x8 bqh1 = *(const bf16x8*)&QsH[rowb + 32 + g * 8];
    const bf16x8 bql0 = *(const bf16x8*)&QsL[rowb + g * 8];
    const bf16x8 bql1 = *(const bf16x8*)&QsL[rowb + 32 + g * 8];

#pragma unroll
    for (int ot = 0; ot < 4; ++ot) {
      f32x4 a = (f32x4){0.f, 0.f, 0.f, 0.f};
      const bf16x8 rh0 = *(const bf16x8*)(rma + ((0 * 4 + ot) * 2 + 0) * 512 + l * 8);
      const bf16x8 rh1 = *(const bf16x8*)(rma + ((0 * 4 + ot) * 2 + 1) * 512 + l * 8);
      const bf16x8 rl0 = *(const bf16x8*)(rma + ((1 * 4 + ot) * 2 + 0) * 512 + l * 8);
      const bf16x8 rl1 = *(const bf16x8*)(rma + ((1 * 4 + ot) * 2 + 1) * 512 + l * 8);
      a = __builtin_amdgcn_mfma_f32_16x16x32_bf16(rh0, bqh0, a, 0, 0, 0);
      a = __builtin_amdgcn_mfma_f32_16x16x32_bf16(rh1, bqh1, a, 0, 0, 0);
      a = __builtin_amdgcn_mfma_f32_16x16x32_bf16(rh0, bql0, a, 0, 0, 0);
      a = __builtin_amdgcn_mfma_f32_16x16x32_bf16(rh1, bql1, a, 0, 0, 0);
      a = __builtin_amdgcn_mfma_f32_16x16x32_bf16(rl0, bqh0, a, 0, 0, 0);
      a = __builtin_amdgcn_mfma_f32_16x16x32_bf16(rl1, bqh1, a, 0, 0, 0);

      const float a0 = f1 * a[0] + rden * rvsv[ot * 4 + 0] + rbv[ot * 4 + 0];
      const float a1 = f1 * a[1] + rden * rvsv[ot * 4 + 1] + rbv[ot * 4 + 1];
      const float a2 = f1 * a[2] + rden * rvsv[ot * 4 + 2] + rbv[ot * 4 + 2];
      const float a3 = f1 * a[3] + rden * rvsv[ot * 4 + 3] + rbv[ot * 4 + 3];
      const uint2 s0 = split2(a0);
      const uint2 s1 = split2(a1);
      const uint2 s2 = split2(a2);
      const uint2 s3 = split2(a3);
      const size_t base =
          (((size_t)(b * 8 + rbr * 4 + ot)) * N_ + (px0 + w * 16 + li)) * 16 + g * 4;
      *(uint2*)(catH + base) = make_uint2(s0.x | (s1.x << 16), s2.x | (s3.x << 16));
      *(uint2*)(catL + base) = make_uint2(s0.y | (s1.y << 16), s2.y | (s3.y << 16));
    }
  }
}

// ================================================================
// prep_wa: conv weights -> A-frag order, split bf16 hi/lo. (unchanged)
// ================================================================
__global__ void prep_wa_kernel(const float* __restrict__ cw,
                               __hip_bfloat16* __restrict__ WA) {
  const int e = blockIdx.x * 256 + threadIdx.x;
  if (e >= 8 * 5 * 2 * 4 * 512) return;
  const int j    = e & 7;
  const int lane = (e >> 3) & 63;
  const int f    = e >> 9;
  const int ot   = f & 3;
  const int v    = (f >> 2) & 1;
  const int s    = (f >> 3) % 5;
  const int c    = (f >> 3) / 5;
  const int o    = ot * 16 + (lane & 15);
  const int g    = lane >> 4;
  const int tap  = 2 * s + (g >> 1);
  float val = 0.f;
  if (tap <= 8) {
    const int ci = c * 16 + (g & 1) * 8 + j;
    val = cw[(size_t)(o * 128 + ci) * 9 + tap];
  }
  __hip_bfloat16 h = __float2bfloat16(val);
  if (v) h = __float2bfloat16(val - __bfloat162float(h));
  WA[e] = h;
}

// ================================================================
// Pass 3: 3x3 conv via MFMA implicit GEMM, split-bf16, T14 pipeline,
// LDS dbuf, (row, ot-half) wave split. (unchanged from round 14 —
// plateaued at ~229 us in the 2-phase structure)
// ================================================================
__global__ __launch_bounds__(512, 4) void conv_mfma_kernel(
    const __hip_bfloat16* __restrict__ catH,
    const __hip_bfloat16* __restrict__ catL,
    const __hip_bfloat16* __restrict__ WA,
    const float* __restrict__ cb,
    float* __restrict__ out)
{
  __shared__ __hip_bfloat16 XsH[2][6 * 68 * 24];
  __shared__ __hip_bfloat16 XsL[2][6 * 68 * 24];

  const int t  = threadIdx.x;
  const int v  = t >> 6;        // wave id 0..7
  const int wr = v >> 1;        // output row 0..3
  const int oh = v & 1;         // ot-half: ots {2oh, 2oh+1}
  const int l  = t & 63;
  const int li = l & 15;
  const int g  = l >> 4;
  const int x0 = blockIdx.x * 64;
  const int y0 = blockIdx.y * 4;
  const int b  = blockIdx.z;

  const bool hasA = (t < 396);
  const int rA = t / 66, cA = t - rA * 66;
  const int gyA = y0 + rA - 1, gxA = x0 + cA - 1;
  const bool okA = hasA && ((unsigned)gyA < 256u) && ((unsigned)gxA < 256u);
  const size_t offA = ((size_t)(gyA * HW_ + gxA)) * 16;
  const int leA = (rA * 68 + cA) * 24;
  const uint4 Z = make_uint4(0u, 0u, 0u, 0u);

  uint4 Ah0, Ah1, Al0, Al1;

  f32x4 acc[2][4];
#pragma unroll
  for (int i = 0; i < 2; ++i)
#pragma unroll
    for (int k = 0; k < 4; ++k) acc[i][k] = (f32x4){0.f, 0.f, 0.f, 0.f};

  {
    const size_t chb = ((size_t)(b * 8 + 0)) * N_ * 16;
    Ah0 = Ah1 = Al0 = Al1 = Z;
    if (okA) {
      const uint4* ph = (const uint4*)(catH + chb + offA);
      Ah0 = ph[0]; Ah1 = ph[1];
      const uint4* pl = (const uint4*)(catL + chb + offA);
      Al0 = pl[0]; Al1 = pl[1];
    }
  }

  for (int c = 0; c < 8; ++c) {
    const int cur = c & 1;
    if (hasA) {
      *(uint4*)(&XsH[cur][leA]) = Ah0; *(uint4*)(&XsH[cur][leA + 8]) = Ah1;
      *(uint4*)(&XsL[cur][leA]) = Al0; *(uint4*)(&XsL[cur][leA + 8]) = Al1;
    }
    if (c < 7) {
      const size_t chb = ((size_t)(b * 8 + c + 1)) * N_ * 16;
      Ah0 = Ah1 = Al0 = Al1 = Z;
      if (okA) {
        const uint4* ph = (const uint4*)(catH + chb + offA);
        Ah0 = ph[0]; Ah1 = ph[1];
        const uint4* pl = (const uint4*)(catL + chb + offA);
        Al0 = pl[0]; Al1 = pl[1];
      }
    }
    __syncthreads();

    const __hip_bfloat16* xh = XsH[cur];
    const __hip_bfloat16* xl = XsL[cur];
    const __hip_bfloat16* wa_c = WA + (size_t)c * 20480;
#pragma unroll
    for (int s = 0; s < 5; ++s) {
      const __hip_bfloat16* wa_s = wa_c + s * 4096 + l * 8;
      bf16x8 aH[2], aL[2];
#pragma unroll
      for (int oi = 0; oi < 2; ++oi) {
        aH[oi] = *(const bf16x8*)(wa_s + (oh * 2 + oi) * 512);
        aL[oi] = *(const bf16x8*)(wa_s + 2048 + (oh * 2 + oi) * 512);
      }

      int tap = 2 * s + (g >> 1);
      if (tap > 8) tap = 0;
      const int ky = tap / 3;
      const int kx = tap - ky * 3;
      const int e0 = ((wr + ky) * 68 + li + kx) * 24 + (g & 1) * 8;

#pragma unroll
      for (int pt = 0; pt < 4; ++pt) {
        const bf16x8 bH = *(const bf16x8*)(&xh[e0 + pt * 384]);
        const bf16x8 bL = *(const bf16x8*)(&xl[e0 + pt * 384]);
#pragma unroll
        for (int oi = 0; oi < 2; ++oi) {
          acc[oi][pt] = __builtin_amdgcn_mfma_f32_16x16x32_bf16(
              aH[oi], bH, acc[oi][pt], 0, 0, 0);
          acc[oi][pt] = __builtin_amdgcn_mfma_f32_16x16x32_bf16(
              aH[oi], bL, acc[oi][pt], 0, 0, 0);
          acc[oi][pt] = __builtin_amdgcn_mfma_f32_16x16x32_bf16(
              aL[oi], bH, acc[oi][pt], 0, 0, 0);
        }
      }
    }
  }

#pragma unroll
  for (int oi = 0; oi < 2; ++oi)
#pragma unroll
    for (int r = 0; r < 4; ++r) {
      const int o = (oh * 2 + oi) * 16 + g * 4 + r;
      const float bv = cb[o];
      float* orow = out + ((size_t)b * 64 + o) * N_ + (size_t)(y0 + wr) * HW_ + x0 + li;
#pragma unroll
      for (int pt = 0; pt < 4; ++pt)
        orow[pt * 16] = acc[oi][pt][r] + bv;
    }
}

// ================================================================
extern "C" void kernel_launch(void* const* d_in, const int* in_sizes, int n_in,
                              void* d_out, int out_size, void* d_ws, size_t ws_size,
                              hipStream_t stream) {
  const float* t1  = (const float*)d_in[0];
  const float* t2  = (const float*)d_in[1];
  const float* q1w = (const float*)d_in[2];
  const float* q1b = (const float*)d_in[3];
  const float* k1w = (const float*)d_in[4];
  const float* k1b = (const float*)d_in[5];
  const float* v1w = (const float*)d_in[6];
  const float* v1b = (const float*)d_in[7];
  const float* r1w = (const float*)d_in[8];
  const float* r1b = (const float*)d_in[9];
  const float* q2w = (const float*)d_in[10];
  const float* q2b = (const float*)d_in[11];
  const float* k2w = (const float*)d_in[12];
  const float* k2b = (const float*)d_in[13];
  const float* v2w = (const float*)d_in[14];
  const float* v2b = (const float*)d_in[15];
  const float* r2w = (const float*)d_in[16];
  const float* r2b = (const float*)d_in[17];
  const float* cw  = (const float*)d_in[18];
  const float* cbp = (const float*)d_in[19];
  float* out = (float*)d_out;

  // ws: [catH 128MB][catL 128MB][partials 16.5MB][derived 264KB]
  // Aliases inside the dead-after-finalize partials region:
  //   WA at +0 (320KB), RMA at +1MB (256KB), QWA at +2MB (32KB).
  // WK (stats weights) aliases catH (dead until attn runs).
  char* ws = (char*)d_ws;
  const size_t catB  = (size_t)B_ * 8 * N_ * 16 * 2;     // 128 MB each
  const size_t partB = (size_t)16 * CHUNKS * STATS * sizeof(float);
  __hip_bfloat16* catHp = (__hip_bfloat16*)ws;
  __hip_bfloat16* catLp = (__hip_bfloat16*)(ws + catB);
  float* part = (float*)(ws + 2 * catB);
  float* der  = (float*)(ws + 2 * catB + partB);
  __hip_bfloat16* WA   = (__hip_bfloat16*)part;                         // alias
  unsigned short* RMAp = (unsigned short*)(ws + 2 * catB + (1u << 20)); // alias
  unsigned short* QWAp = (unsigned short*)(ws + 2 * catB + (2u << 20)); // alias
  unsigned short* WKp  = (unsigned short*)ws;                           // alias (catH)

  prep_proj_kernel<<<dim3(64), 256, 0, stream>>>(k1w, v1w, k2w, v2w, WKp);
  stats_mfma_kernel<<<dim3(CHUNKS, B_, 2), 256, 0, stream>>>(
      t1, t2, k1b, v1b, k2b, v2b, WKp, part);
  finalize_kernel<<<dim3(16), 256, 0, stream>>>(part, r1w, r2w, der);
  qw_prep_kernel<<<dim3(64), 256, 0, stream>>>(q1w, q2w, QWAp);
  rm_prep_kernel<<<dim3(512), 256, 0, stream>>>(der, RMAp);
  prep_wa_kernel<<<dim3(640), 256, 0, stream>>>(cw, WA);
  attn_mfma_kernel<<<dim3(CHUNKS, B_, 2), 256, 0, stream>>>(
      t1, t2, q1b, q2b, r1b, r2b, der, QWAp, RMAp, catHp, catLp);
  conv_mfma_kernel<<<dim3(4, 64, B_), 512, 0, stream>>>(
      catHp, catLp, WA, cbp, out);
}

// Round 17
// 497.405 us; speedup vs baseline: 1.0996x; 1.0020x over previous
//
#include <hip/hip_runtime.h>
#include <hip/hip_bf16.h>

// Problem constants (fixed by setup_inputs)
constexpr int B_ = 8;
constexpr int C_ = 64;      // input channels = KC = VC = 64
constexpr int N_ = 65536;   // H*W = 256*256
constexpr int HW_ = 256;
constexpr float EPSF = 1e-6f;
constexpr int STATS = 4224; // 4096 matrix + 64 ksum + 64 vsum
constexpr int CHUNKS = 64;  // stats blocks per (branch,batch)

typedef __attribute__((ext_vector_type(8))) short bf16x8;
typedef __attribute__((ext_vector_type(4))) float f32x4;

// RNE fp32 -> bf16 bits, pure bit arithmetic (no address-taken locals)
__device__ __forceinline__ unsigned short f2bf(float f) {
  const unsigned u = __float_as_uint(f);
  return (unsigned short)((u + 0x7fffu + ((u >> 16) & 1u)) >> 16);
}

// Cheap TRUNCATION hi/lo split: the pair (hi,lo) represents v to
// <= 2^-16|v| (residual subtraction is exact). 4 VALU ops vs ~11 RNE.
__device__ __forceinline__ uint2 split2(float v) {
  const unsigned u = __float_as_uint(v);
  const float lo = v - __uint_as_float(u & 0xffff0000u);
  return make_uint2(u >> 16, __float_as_uint(lo) >> 16);
}

// ================================================================
// prep_proj: K/V projection weights -> MFMA A-fragment order, bf16.
// WK[r(2)][kv(2)][ot(4)][ks(2)][lane(64)][j(8)]  (unchanged)
// ================================================================
__global__ void prep_proj_kernel(const float* __restrict__ k1w,
                                 const float* __restrict__ v1w,
                                 const float* __restrict__ k2w,
                                 const float* __restrict__ v2w,
                                 unsigned short* __restrict__ WK) {
  const int e = blockIdx.x * 256 + threadIdx.x;   // 16384 total
  if (e >= 16384) return;
  const int j    = e & 7;
  const int lane = (e >> 3) & 63;
  const int ks   = (e >> 9) & 1;
  const int ot   = (e >> 10) & 3;
  const int kv   = (e >> 12) & 1;
  const int r    = (e >> 13) & 1;
  const int m    = ot * 16 + (lane & 15);
  const int ch   = ks * 32 + ((lane >> 4) & 3) * 8 + j;
  const float* w = r ? (kv ? v2w : k2w) : (kv ? v1w : k1w);
  WK[e] = f2bf(w[m * 64 + ch]);
}

// ================================================================
// qw_prep: Q projection weights -> A-frag order, bf16 HI/LO planes.
// ================================================================
__global__ void qw_prep_kernel(const float* __restrict__ q1w,
                               const float* __restrict__ q2w,
                               unsigned short* __restrict__ QWA) {
  const int e = blockIdx.x * 256 + threadIdx.x;
  if (e >= 16384) return;
  const int j    = e & 7;
  const int lane = (e >> 3) & 63;
  const int ks   = (e >> 9) & 1;
  const int ot   = (e >> 10) & 3;
  const int v    = (e >> 12) & 1;
  const int r    = (e >> 13) & 1;
  const int m    = ot * 16 + (lane & 15);
  const int ch   = ks * 32 + ((lane >> 4) & 3) * 8 + j;
  const float val = (r ? q2w : q1w)[m * 64 + ch];
  unsigned short h = f2bf(val);
  if (v) h = f2bf(val - __uint_as_float((unsigned)h << 16));
  QWA[e] = h;
}

// ================================================================
// rm_prep: rm (= derived[bb][o*64+m]) -> A-frag order bf16 HI/LO.
// ================================================================
__global__ void rm_prep_kernel(const float* __restrict__ derived,
                               unsigned short* __restrict__ RMA) {
  const int e = blockIdx.x * 256 + threadIdx.x;   // 131072 total
  if (e >= 131072) return;
  const int j    = e & 7;
  const int lane = (e >> 3) & 63;
  const int ks   = (e >> 9) & 1;
  const int ot   = (e >> 10) & 3;
  const int v    = (e >> 12) & 1;
  const int bb   = e >> 13;
  const int o    = ot * 16 + (lane & 15);
  const int m    = ks * 32 + ((lane >> 4) & 3) * 8 + j;
  const float val = derived[(size_t)bb * STATS + o * 64 + m];
  unsigned short h = f2bf(val);
  if (v) h = f2bf(val - __uint_as_float((unsigned)h << 16));
  RMA[e] = h;
}

// ================================================================
// Pass 1 (MFMA stats) — round-14 form (proven best). Unchanged.
// ================================================================
__global__ __launch_bounds__(256, 2) void stats_mfma_kernel(
    const float* __restrict__ t1, const float* __restrict__ t2,
    const float* __restrict__ k1b, const float* __restrict__ v1b,
    const float* __restrict__ k2b, const float* __restrict__ v2b,
    const unsigned short* __restrict__ WK,
    float* __restrict__ partials)
{
  const int chunk = blockIdx.x;
  const int b = blockIdx.y;
  const int r = blockIdx.z;
  const float* x  = (r ? t2 : t1) + (size_t)b * C_ * N_;
  const float* kb = r ? k2b : k1b;
  const float* vb = r ? v2b : v1b;
  const unsigned short* WKr = WK + r * 8192;

  __shared__ unsigned short Xs[64 * 72];
  __shared__ unsigned short Ks[64 * 72];
  __shared__ unsigned short Vs[64 * 72];

  const int t  = threadIdx.x;
  const int w  = t >> 6;
  const int l  = t & 63;
  const int li = l & 15;
  const int g  = l >> 4;

  float kbv[4][4], vbv[4][4];
#pragma unroll
  for (int ot = 0; ot < 4; ++ot)
#pragma unroll
    for (int rg = 0; rg < 4; ++rg) {
      kbv[ot][rg] = kb[ot * 16 + g * 4 + rg];
      vbv[ot][rg] = vb[ot * 16 + g * 4 + rg];
    }

  bf16x8 ones;
#pragma unroll
  for (int j = 0; j < 8; ++j) ones[j] = (short)0x3F80;

  f32x4 accM[4];
#pragma unroll
  for (int ct = 0; ct < 4; ++ct) accM[ct] = (f32x4){0.f, 0.f, 0.f, 0.f};
  f32x4 accSk = (f32x4){0.f, 0.f, 0.f, 0.f};
  f32x4 accSv = (f32x4){0.f, 0.f, 0.f, 0.f};

  for (int it = 0; it < 16; ++it) {
    const int px0 = chunk * 1024 + it * 64;
    __syncthreads();
    {
      const int ch = t >> 2;
      const int ps = t & 3;
      const float* src = x + (size_t)ch * N_ + px0 + ps * 16;
      const float4 f0 = ((const float4*)src)[0];
      const float4 f1 = ((const float4*)src)[1];
      const float4 f2 = ((const float4*)src)[2];
      const float4 f3 = ((const float4*)src)[3];
      float v[16] = {f0.x, f0.y, f0.z, f0.w, f1.x, f1.y, f1.z, f1.w,
                     f2.x, f2.y, f2.z, f2.w, f3.x, f3.y, f3.z, f3.w};
      unsigned short* dst = &Xs[(ps * 16) * 72 + (ch ^ (ps << 4))];
#pragma unroll
      for (int i = 0; i < 16; ++i) dst[i * 72] = f2bf(v[i]);
    }
    __syncthreads();

    bf16x8 bx0 = *(const bf16x8*)&Xs[(w * 16 + li) * 72 + ((g * 8) ^ (w << 4))];
    bf16x8 bx1 = *(const bf16x8*)&Xs[(w * 16 + li) * 72 + ((32 + g * 8) ^ (w << 4))];

    f32x4 ka[4];
#pragma unroll
    for (int ot = 0; ot < 4; ++ot) {
      f32x4 a = (f32x4){0.f, 0.f, 0.f, 0.f};
      const bf16x8 w0 = *(const bf16x8*)(WKr + ((ot * 2 + 0) * 64 + l) * 8);
      const bf16x8 w1 = *(const bf16x8*)(WKr + ((ot * 2 + 1) * 64 + l) * 8);
      a = __builtin_amdgcn_mfma_f32_16x16x32_bf16(w0, bx0, a, 0, 0, 0);
      a = __builtin_amdgcn_mfma_f32_16x16x32_bf16(w1, bx1, a, 0, 0, 0);
      ka[ot] = a;
    }
    float ss = 0.f;
#pragma unroll
    for (int ot = 0; ot < 4; ++ot)
#pragma unroll
      for (int rg = 0; rg < 4; ++rg) {
        const float v2 = ka[ot][rg] + kbv[ot][rg];
        ka[ot][rg] = v2;
        ss += v2 * v2;
      }
    ss += __shfl_xor(ss, 16);
    ss += __shfl_xor(ss, 32);
    const float inv = rsqrtf(ss);
#pragma unroll
    for (int ot = 0; ot < 4; ++ot)
#pragma unroll
      for (int rg = 0; rg < 4; ++rg)
        Ks[(ot * 16 + g * 4 + rg) * 72 + w * 16 + li] = f2bf(ka[ot][rg] * inv);

#pragma unroll
    for (int ot = 0; ot < 4; ++ot) {
      f32x4 a = (f32x4){0.f, 0.f, 0.f, 0.f};
      const bf16x8 w0 = *(const bf16x8*)(WKr + 4096 + ((ot * 2 + 0) * 64 + l) * 8);
      const bf16x8 w1 = *(const bf16x8*)(WKr + 4096 + ((ot * 2 + 1) * 64 + l) * 8);
      a = __builtin_amdgcn_mfma_f32_16x16x32_bf16(w0, bx0, a, 0, 0, 0);
      a = __builtin_amdgcn_mfma_f32_16x16x32_bf16(w1, bx1, a, 0, 0, 0);
#pragma unroll
      for (int rg = 0; rg < 4; ++rg)
        Vs[(ot * 16 + g * 4 + rg) * 72 + w * 16 + li] = f2bf(a[rg] + vbv[ot][rg]);
    }
    __syncthreads();

#pragma unroll
    for (int ks = 0; ks < 2; ++ks) {
      const int ko = ks * 32 + g * 8;
      const bf16x8 aK = *(const bf16x8*)&Ks[(w * 16 + li) * 72 + ko];
      const bf16x8 aV = *(const bf16x8*)&Vs[(w * 16 + li) * 72 + ko];
      accSk = __builtin_amdgcn_mfma_f32_16x16x32_bf16(aK, ones, accSk, 0, 0, 0);
      accSv = __builtin_amdgcn_mfma_f32_16x16x32_bf16(aV, ones, accSv, 0, 0, 0);
#pragma unroll
      for (int ct = 0; ct < 4; ++ct) {
        const bf16x8 bV = *(const bf16x8*)&Vs[(ct * 16 + li) * 72 + ko];
        accM[ct] = __builtin_amdgcn_mfma_f32_16x16x32_bf16(aK, bV, accM[ct], 0, 0, 0);
      }
    }
  }

  float* pb = partials + ((size_t)(r * B_ + b) * CHUNKS + chunk) * STATS;
#pragma unroll
  for (int ct = 0; ct < 4; ++ct)
#pragma unroll
    for (int rg = 0; rg < 4; ++rg)
      pb[(w * 16 + g * 4 + rg) * 64 + ct * 16 + li] = accM[ct][rg];
  if (li == 0) {
#pragma unroll
    for (int rg = 0; rg < 4; ++rg) {
      pb[4096 + w * 16 + g * 4 + rg] = accSk[rg];
      pb[4160 + w * 16 + g * 4 + rg] = accSv[rg];
    }
  }
}

// ================================================================
// Finalize: reduce partials, fold r_w in. (unchanged)
// ================================================================
__global__ void finalize_kernel(const float* __restrict__ partials,
                                const float* __restrict__ r1w,
                                const float* __restrict__ r2w,
                                float* __restrict__ derived)
{
  const int bb = blockIdx.x;
  const int r = bb >> 3;
  const float* rw = r ? r2w : r1w;
  __shared__ float mat[4096];
  __shared__ float ks[64], vs[64];
  const int t = threadIdx.x;
  const float* pb = partials + (size_t)bb * CHUNKS * STATS;
  for (int e = t; e < STATS; e += 256) {
    float s = 0.f;
    for (int j = 0; j < CHUNKS; ++j) s += pb[(size_t)j * STATS + e];
    if (e < 4096) mat[e] = s;
    else if (e < 4160) ks[e - 4096] = s;
    else vs[e - 4160] = s;
  }
  __syncthreads();
  float* der = derived + (size_t)bb * STATS;
  for (int e = t; e < 4096; e += 256) {
    const int o = e >> 6, m = e & 63;
    float s = 0.f;
    for (int c = 0; c < 64; ++c) s += rw[o * 64 + c] * mat[m * 64 + c];
    der[e] = s;
  }
  if (t < 64) {
    float s = 0.f;
    for (int c = 0; c < 64; ++c) s += rw[t * 64 + c] * vs[c];
    der[4096 + t] = s;
    der[4160 + t] = ks[t] + EPSF;
  }
}

// ================================================================
// Pass 2 (MFMA attn) — round-16 form (truncation splits). Unchanged.
// ================================================================
__global__ __launch_bounds__(256, 2) void attn_mfma_kernel(
    const float* __restrict__ t1, const float* __restrict__ t2,
    const float* __restrict__ q1b, const float* __restrict__ q2b,
    const float* __restrict__ r1b, const float* __restrict__ r2b,
    const float* __restrict__ derived,
    const unsigned short* __restrict__ QWA,
    const unsigned short* __restrict__ RMA,
    __hip_bfloat16* __restrict__ catH, __hip_bfloat16* __restrict__ catL)
{
  const int chunk = blockIdx.x;
  const int b = blockIdx.y;
  const int rbr = blockIdx.z;
  const float* x  = (rbr ? t2 : t1) + (size_t)b * C_ * N_;
  const float* qb = rbr ? q2b : q1b;
  const float* rb = rbr ? r2b : r1b;
  const int bb = rbr * B_ + b;
  const float* der = derived + (size_t)bb * STATS;
  const unsigned short* qwa = QWA + rbr * 8192;
  const unsigned short* rma = RMA + (size_t)bb * 8192;

  __shared__ unsigned short XsH[64 * 72];
  __shared__ unsigned short XsL[64 * 72];
  __shared__ unsigned short QsH[64 * 72];
  __shared__ unsigned short QsL[64 * 72];

  const int t  = threadIdx.x;
  const int w  = t >> 6;
  const int l  = t & 63;
  const int li = l & 15;
  const int g  = l >> 4;

  float qbv[16], ksev[16], rvsv[16], rbv[16];
#pragma unroll
  for (int ot = 0; ot < 4; ++ot)
#pragma unroll
    for (int rg = 0; rg < 4; ++rg) {
      const int row = ot * 16 + g * 4 + rg;
      qbv[ot * 4 + rg]  = qb[row];
      ksev[ot * 4 + rg] = der[4160 + row];
      rvsv[ot * 4 + rg] = der[4096 + row];
      rbv[ot * 4 + rg]  = rb[row];
    }

#pragma clang loop unroll(disable)
  for (int it = 0; it < 16; ++it) {
    const int px0 = chunk * 1024 + it * 64;
    __syncthreads();
    {
      const int ch = t >> 2;
      const int ps = t & 3;
      const float* src = x + (size_t)ch * N_ + px0 + ps * 16;
      const float4 f0 = ((const float4*)src)[0];
      const float4 f1v = ((const float4*)src)[1];
      const float4 f2v = ((const float4*)src)[2];
      const float4 f3v = ((const float4*)src)[3];
      float v[16] = {f0.x, f0.y, f0.z, f0.w, f1v.x, f1v.y, f1v.z, f1v.w,
                     f2v.x, f2v.y, f2v.z, f2v.w, f3v.x, f3v.y, f3v.z, f3v.w};
      const int col = ch ^ (ps << 4);
      unsigned short* dH = &XsH[(ps * 16) * 72 + col];
      unsigned short* dL = &XsL[(ps * 16) * 72 + col];
#pragma unroll
      for (int i = 0; i < 16; ++i) {
        const uint2 hl = split2(v[i]);
        dH[i * 72] = (unsigned short)hl.x;
        dL[i * 72] = (unsigned short)hl.y;
      }
    }
    __syncthreads();

    const int rowb = (w * 16 + li) * 72;
    const bf16x8 bxh0 = *(const bf16x8*)&XsH[rowb + ((g * 8) ^ (w << 4))];
    const bf16x8 bxh1 = *(const bf16x8*)&XsH[rowb + ((32 + g * 8) ^ (w << 4))];
    const bf16x8 bxl0 = *(const bf16x8*)&XsL[rowb + ((g * 8) ^ (w << 4))];
    const bf16x8 bxl1 = *(const bf16x8*)&XsL[rowb + ((32 + g * 8) ^ (w << 4))];

    float q[16];
#pragma unroll
    for (int ot = 0; ot < 4; ++ot) {
      f32x4 a = (f32x4){0.f, 0.f, 0.f, 0.f};
      const bf16x8 wh0 = *(const bf16x8*)(qwa + ((0 * 4 + ot) * 2 + 0) * 512 + l * 8);
      const bf16x8 wh1 = *(const bf16x8*)(qwa + ((0 * 4 + ot) * 2 + 1) * 512 + l * 8);
      const bf16x8 wl0 = *(const bf16x8*)(qwa + ((1 * 4 + ot) * 2 + 0) * 512 + l * 8);
      const bf16x8 wl1 = *(const bf16x8*)(qwa + ((1 * 4 + ot) * 2 + 1) * 512 + l * 8);
      a = __builtin_amdgcn_mfma_f32_16x16x32_bf16(wh0, bxh0, a, 0, 0, 0);
      a = __builtin_amdgcn_mfma_f32_16x16x32_bf16(wh1, bxh1, a, 0, 0, 0);
      a = __builtin_amdgcn_mfma_f32_16x16x32_bf16(wh0, bxl0, a, 0, 0, 0);
      a = __builtin_amdgcn_mfma_f32_16x16x32_bf16(wh1, bxl1, a, 0, 0, 0);
      a = __builtin_amdgcn_mfma_f32_16x16x32_bf16(wl0, bxh0, a, 0, 0, 0);
      a = __builtin_amdgcn_mfma_f32_16x16x32_bf16(wl1, bxh1, a, 0, 0, 0);
#pragma unroll
      for (int rg = 0; rg < 4; ++rg) q[ot * 4 + rg] = a[rg] + qbv[ot * 4 + rg];
    }

    float ss = 0.f, d = 0.f;
#pragma unroll
    for (int i = 0; i < 16; ++i) { ss += q[i] * q[i]; d += q[i] * ksev[i]; }
    ss += __shfl_xor(ss, 16);  ss += __shfl_xor(ss, 32);
    d  += __shfl_xor(d, 16);   d  += __shfl_xor(d, 32);
    const float inv = rsqrtf(ss);
    const float rden = 1.0f / (65536.0f + inv * d);
    const float f1 = rden * inv;

#pragma unroll
    for (int ot = 0; ot < 4; ++ot) {
      const uint2 s0 = split2(q[ot * 4 + 0]);
      const uint2 s1 = split2(q[ot * 4 + 1]);
      const uint2 s2 = split2(q[ot * 4 + 2]);
      const uint2 s3 = split2(q[ot * 4 + 3]);
      const int off = (w * 16 + li) * 72 + ot * 16 + g * 4;
      *(uint2*)&QsH[off] = make_uint2(s0.x | (s1.x << 16), s2.x | (s3.x << 16));
      *(uint2*)&QsL[off] = make_uint2(s0.y | (s1.y << 16), s2.y | (s3.y << 16));
    }

    const bf16x8 bqh0 = *(const bf16x8*)&QsH[rowb + g * 8];
    const bf16x8 bqh1 = *(const bf16x8*)&QsH[rowb + 32 + g * 8];
    const bf16x8 bql0 = *(const bf16x8*)&QsL[rowb + g * 8];
    const bf16x8 bql1 = *(const bf16x8*)&QsL[rowb + 32 + g * 8];

#pragma unroll
    for (int ot = 0; ot < 4; ++ot) {
      f32x4 a = (f32x4){0.f, 0.f, 0.f, 0.f};
      const bf16x8 rh0 = *(const bf16x8*)(rma + ((0 * 4 + ot) * 2 + 0) * 512 + l * 8);
      const bf16x8 rh1 = *(const bf16x8*)(rma + ((0 * 4 + ot) * 2 + 1) * 512 + l * 8);
      const bf16x8 rl0 = *(const bf16x8*)(rma + ((1 * 4 + ot) * 2 + 0) * 512 + l * 8);
      const bf16x8 rl1 = *(const bf16x8*)(rma + ((1 * 4 + ot) * 2 + 1) * 512 + l * 8);
      a = __builtin_amdgcn_mfma_f32_16x16x32_bf16(rh0, bqh0, a, 0, 0, 0);
      a = __builtin_amdgcn_mfma_f32_16x16x32_bf16(rh1, bqh1, a, 0, 0, 0);
      a = __builtin_amdgcn_mfma_f32_16x16x32_bf16(rh0, bql0, a, 0, 0, 0);
      a = __builtin_amdgcn_mfma_f32_16x16x32_bf16(rh1, bql1, a, 0, 0, 0);
      a = __builtin_amdgcn_mfma_f32_16x16x32_bf16(rl0, bqh0, a, 0, 0, 0);
      a = __builtin_amdgcn_mfma_f32_16x16x32_bf16(rl1, bqh1, a, 0, 0, 0);

      const float a0 = f1 * a[0] + rden * rvsv[ot * 4 + 0] + rbv[ot * 4 + 0];
      const float a1 = f1 * a[1] + rden * rvsv[ot * 4 + 1] + rbv[ot * 4 + 1];
      const float a2 = f1 * a[2] + rden * rvsv[ot * 4 + 2] + rbv[ot * 4 + 2];
      const float a3 = f1 * a[3] + rden * rvsv[ot * 4 + 3] + rbv[ot * 4 + 3];
      const uint2 s0 = split2(a0);
      const uint2 s1 = split2(a1);
      const uint2 s2 = split2(a2);
      const uint2 s3 = split2(a3);
      const size_t base =
          (((size_t)(b * 8 + rbr * 4 + ot)) * N_ + (px0 + w * 16 + li)) * 16 + g * 4;
      *(uint2*)(catH + base) = make_uint2(s0.x | (s1.x << 16), s2.x | (s3.x << 16));
      *(uint2*)(catL + base) = make_uint2(s0.y | (s1.y << 16), s2.y | (s3.y << 16));
    }
  }
}

// ================================================================
// prep_wa: conv weights -> A-frag order, split bf16 hi/lo. (unchanged)
// ================================================================
__global__ void prep_wa_kernel(const float* __restrict__ cw,
                               __hip_bfloat16* __restrict__ WA) {
  const int e = blockIdx.x * 256 + threadIdx.x;
  if (e >= 8 * 5 * 2 * 4 * 512) return;
  const int j    = e & 7;
  const int lane = (e >> 3) & 63;
  const int f    = e >> 9;
  const int ot   = f & 3;
  const int v    = (f >> 2) & 1;
  const int s    = (f >> 3) % 5;
  const int c    = (f >> 3) / 5;
  const int o    = ot * 16 + (lane & 15);
  const int g    = lane >> 4;
  const int tap  = 2 * s + (g >> 1);
  float val = 0.f;
  if (tap <= 8) {
    const int ci = c * 16 + (g & 1) * 8 + j;
    val = cw[(size_t)(o * 128 + ci) * 9 + tap];
  }
  __hip_bfloat16 h = __float2bfloat16(val);
  if (v) h = __float2bfloat16(val - __bfloat162float(h));
  WA[e] = h;
}

// ================================================================
// Pass 3: 3x3 conv via MFMA implicit GEMM, split-bf16, LDS dbuf.
// ROUND-17 FIX: round-14 issued the c+1 prefetch loads BEFORE the
// barrier — the compiler's mandatory s_waitcnt vmcnt(0) before
// s_barrier drained them there, serializing loads against compute
// (T14 silently dead; explains r14 == r12 perf). Now: write ->
// barrier -> ISSUE(c+1) -> compute. Loads fly across the whole
// compute phase; the only wait is a per-wave vmcnt before next
// iteration's ds_write (not a block-wide drain).
// ================================================================
__global__ __launch_bounds__(512, 4) void conv_mfma_kernel(
    const __hip_bfloat16* __restrict__ catH,
    const __hip_bfloat16* __restrict__ catL,
    const __hip_bfloat16* __restrict__ WA,
    const float* __restrict__ cb,
    float* __restrict__ out)
{
  __shared__ __hip_bfloat16 XsH[2][6 * 68 * 24];
  __shared__ __hip_bfloat16 XsL[2][6 * 68 * 24];

  const int t  = threadIdx.x;
  const int v  = t >> 6;        // wave id 0..7
  const int wr = v >> 1;        // output row 0..3
  const int oh = v & 1;         // ot-half: ots {2oh, 2oh+1}
  const int l  = t & 63;
  const int li = l & 15;
  const int g  = l >> 4;
  const int x0 = blockIdx.x * 64;
  const int y0 = blockIdx.y * 4;
  const int b  = blockIdx.z;

  const bool hasA = (t < 396);
  const int rA = t / 66, cA = t - rA * 66;
  const int gyA = y0 + rA - 1, gxA = x0 + cA - 1;
  const bool okA = hasA && ((unsigned)gyA < 256u) && ((unsigned)gxA < 256u);
  const size_t offA = ((size_t)(gyA * HW_ + gxA)) * 16;
  const int leA = (rA * 68 + cA) * 24;
  const uint4 Z = make_uint4(0u, 0u, 0u, 0u);

  uint4 Ah0, Ah1, Al0, Al1;

  f32x4 acc[2][4];
#pragma unroll
  for (int i = 0; i < 2; ++i)
#pragma unroll
    for (int k = 0; k < 4; ++k) acc[i][k] = (f32x4){0.f, 0.f, 0.f, 0.f};

  {
    const size_t chb = ((size_t)(b * 8 + 0)) * N_ * 16;
    Ah0 = Ah1 = Al0 = Al1 = Z;
    if (okA) {
      const uint4* ph = (const uint4*)(catH + chb + offA);
      Ah0 = ph[0]; Ah1 = ph[1];
      const uint4* pl = (const uint4*)(catL + chb + offA);
      Al0 = pl[0]; Al1 = pl[1];
    }
  }

  for (int c = 0; c < 8; ++c) {
    const int cur = c & 1;
    // ---- write-late: staged regs (chunk c) -> buf[cur]
    if (hasA) {
      *(uint4*)(&XsH[cur][leA]) = Ah0; *(uint4*)(&XsH[cur][leA + 8]) = Ah1;
      *(uint4*)(&XsL[cur][leA]) = Al0; *(uint4*)(&XsL[cur][leA + 8]) = Al1;
    }
    __syncthreads();             // buf[cur] visible to all waves
    // ---- issue-early AFTER the barrier: loads overlap COMPUTE(c)
    if (c < 7) {
      const size_t chb = ((size_t)(b * 8 + c + 1)) * N_ * 16;
      Ah0 = Ah1 = Al0 = Al1 = Z;
      if (okA) {
        const uint4* ph = (const uint4*)(catH + chb + offA);
        Ah0 = ph[0]; Ah1 = ph[1];
        const uint4* pl = (const uint4*)(catL + chb + offA);
        Al0 = pl[0]; Al1 = pl[1];
      }
    }

    // ---- COMPUTE(c): this wave covers ots {2oh, 2oh+1}, 4 pt
    const __hip_bfloat16* xh = XsH[cur];
    const __hip_bfloat16* xl = XsL[cur];
    const __hip_bfloat16* wa_c = WA + (size_t)c * 20480;
#pragma unroll
    for (int s = 0; s < 5; ++s) {
      const __hip_bfloat16* wa_s = wa_c + s * 4096 + l * 8;
      bf16x8 aH[2], aL[2];
#pragma unroll
      for (int oi = 0; oi < 2; ++oi) {
        aH[oi] = *(const bf16x8*)(wa_s + (oh * 2 + oi) * 512);
        aL[oi] = *(const bf16x8*)(wa_s + 2048 + (oh * 2 + oi) * 512);
      }

      int tap = 2 * s + (g >> 1);
      if (tap > 8) tap = 0;
      const int ky = tap / 3;
      const int kx = tap - ky * 3;
      const int e0 = ((wr + ky) * 68 + li + kx) * 24 + (g & 1) * 8;

#pragma unroll
      for (int pt = 0; pt < 4; ++pt) {
        const bf16x8 bH = *(const bf16x8*)(&xh[e0 + pt * 384]);
        const bf16x8 bL = *(const bf16x8*)(&xl[e0 + pt * 384]);
#pragma unroll
        for (int oi = 0; oi < 2; ++oi) {
          acc[oi][pt] = __builtin_amdgcn_mfma_f32_16x16x32_bf16(
              aH[oi], bH, acc[oi][pt], 0, 0, 0);
          acc[oi][pt] = __builtin_amdgcn_mfma_f32_16x16x32_bf16(
              aH[oi], bL, acc[oi][pt], 0, 0, 0);
          acc[oi][pt] = __builtin_amdgcn_mfma_f32_16x16x32_bf16(
              aL[oi], bH, acc[oi][pt], 0, 0, 0);
        }
      }
    }
  }

#pragma unroll
  for (int oi = 0; oi < 2; ++oi)
#pragma unroll
    for (int r = 0; r < 4; ++r) {
      const int o = (oh * 2 + oi) * 16 + g * 4 + r;
      const float bv = cb[o];
      float* orow = out + ((size_t)b * 64 + o) * N_ + (size_t)(y0 + wr) * HW_ + x0 + li;
#pragma unroll
      for (int pt = 0; pt < 4; ++pt)
        orow[pt * 16] = acc[oi][pt][r] + bv;
    }
}

// ================================================================
extern "C" void kernel_launch(void* const* d_in, const int* in_sizes, int n_in,
                              void* d_out, int out_size, void* d_ws, size_t ws_size,
                              hipStream_t stream) {
  const float* t1  = (const float*)d_in[0];
  const float* t2  = (const float*)d_in[1];
  const float* q1w = (const float*)d_in[2];
  const float* q1b = (const float*)d_in[3];
  const float* k1w = (const float*)d_in[4];
  const float* k1b = (const float*)d_in[5];
  const float* v1w = (const float*)d_in[6];
  const float* v1b = (const float*)d_in[7];
  const float* r1w = (const float*)d_in[8];
  const float* r1b = (const float*)d_in[9];
  const float* q2w = (const float*)d_in[10];
  const float* q2b = (const float*)d_in[11];
  const float* k2w = (const float*)d_in[12];
  const float* k2b = (const float*)d_in[13];
  const float* v2w = (const float*)d_in[14];
  const float* v2b = (const float*)d_in[15];
  const float* r2w = (const float*)d_in[16];
  const float* r2b = (const float*)d_in[17];
  const float* cw  = (const float*)d_in[18];
  const float* cbp = (const float*)d_in[19];
  float* out = (float*)d_out;

  // ws: [catH 128MB][catL 128MB][partials 16.5MB][derived 264KB]
  // Aliases inside the dead-after-finalize partials region:
  //   WA at +0 (320KB), RMA at +1MB (256KB), QWA at +2MB (32KB).
  // WK (stats weights) aliases catH (dead until attn runs).
  char* ws = (char*)d_ws;
  const size_t catB  = (size_t)B_ * 8 * N_ * 16 * 2;     // 128 MB each
  const size_t partB = (size_t)16 * CHUNKS * STATS * sizeof(float);
  __hip_bfloat16* catHp = (__hip_bfloat16*)ws;
  __hip_bfloat16* catLp = (__hip_bfloat16*)(ws + catB);
  float* part = (float*)(ws + 2 * catB);
  float* der  = (float*)(ws + 2 * catB + partB);
  __hip_bfloat16* WA   = (__hip_bfloat16*)part;                         // alias
  unsigned short* RMAp = (unsigned short*)(ws + 2 * catB + (1u << 20)); // alias
  unsigned short* QWAp = (unsigned short*)(ws + 2 * catB + (2u << 20)); // alias
  unsigned short* WKp  = (unsigned short*)ws;                           // alias (catH)

  prep_proj_kernel<<<dim3(64), 256, 0, stream>>>(k1w, v1w, k2w, v2w, WKp);
  stats_mfma_kernel<<<dim3(CHUNKS, B_, 2), 256, 0, stream>>>(
      t1, t2, k1b, v1b, k2b, v2b, WKp, part);
  finalize_kernel<<<dim3(16), 256, 0, stream>>>(part, r1w, r2w, der);
  qw_prep_kernel<<<dim3(64), 256, 0, stream>>>(q1w, q2w, QWAp);
  rm_prep_kernel<<<dim3(512), 256, 0, stream>>>(der, RMAp);
  prep_wa_kernel<<<dim3(640), 256, 0, stream>>>(cw, WA);
  attn_mfma_kernel<<<dim3(CHUNKS, B_, 2), 256, 0, stream>>>(
      t1, t2, q1b, q2b, r1b, r2b, der, QWAp, RMAp, catHp, catLp);
  conv_mfma_kernel<<<dim3(4, 64, B_), 512, 0, stream>>>(
      catHp, catLp, WA, cbp, out);
}

// Round 18
// 495.947 us; speedup vs baseline: 1.1028x; 1.0029x over previous
//
#include <hip/hip_runtime.h>
#include <hip/hip_bf16.h>

// Problem constants (fixed by setup_inputs)
constexpr int B_ = 8;
constexpr int C_ = 64;      // input channels = KC = VC = 64
constexpr int N_ = 65536;   // H*W = 256*256
constexpr int HW_ = 256;
constexpr float EPSF = 1e-6f;
constexpr int STATS = 4224; // 4096 matrix + 64 ksum + 64 vsum
constexpr int CHUNKS = 64;  // stats blocks per (branch,batch)

typedef __attribute__((ext_vector_type(8))) short bf16x8;
typedef __attribute__((ext_vector_type(4))) float f32x4;

// RNE fp32 -> bf16 bits, pure bit arithmetic (no address-taken locals)
__device__ __forceinline__ unsigned short f2bf(float f) {
  const unsigned u = __float_as_uint(f);
  return (unsigned short)((u + 0x7fffu + ((u >> 16) & 1u)) >> 16);
}

// Cheap TRUNCATION hi/lo split: the pair (hi,lo) represents v to
// <= 2^-16|v| (residual subtraction is exact). 4 VALU ops vs ~11 RNE.
__device__ __forceinline__ uint2 split2(float v) {
  const unsigned u = __float_as_uint(v);
  const float lo = v - __uint_as_float(u & 0xffff0000u);
  return make_uint2(u >> 16, __float_as_uint(lo) >> 16);
}

// ================================================================
// prep_proj: K/V projection weights -> MFMA A-fragment order, bf16.
// WK[r(2)][kv(2)][ot(4)][ks(2)][lane(64)][j(8)]  (unchanged)
// ================================================================
__global__ void prep_proj_kernel(const float* __restrict__ k1w,
                                 const float* __restrict__ v1w,
                                 const float* __restrict__ k2w,
                                 const float* __restrict__ v2w,
                                 unsigned short* __restrict__ WK) {
  const int e = blockIdx.x * 256 + threadIdx.x;   // 16384 total
  if (e >= 16384) return;
  const int j    = e & 7;
  const int lane = (e >> 3) & 63;
  const int ks   = (e >> 9) & 1;
  const int ot   = (e >> 10) & 3;
  const int kv   = (e >> 12) & 1;
  const int r    = (e >> 13) & 1;
  const int m    = ot * 16 + (lane & 15);
  const int ch   = ks * 32 + ((lane >> 4) & 3) * 8 + j;
  const float* w = r ? (kv ? v2w : k2w) : (kv ? v1w : k1w);
  WK[e] = f2bf(w[m * 64 + ch]);
}

// ================================================================
// qw_prep: Q projection weights -> A-frag order, bf16 HI/LO planes.
// ================================================================
__global__ void qw_prep_kernel(const float* __restrict__ q1w,
                               const float* __restrict__ q2w,
                               unsigned short* __restrict__ QWA) {
  const int e = blockIdx.x * 256 + threadIdx.x;
  if (e >= 16384) return;
  const int j    = e & 7;
  const int lane = (e >> 3) & 63;
  const int ks   = (e >> 9) & 1;
  const int ot   = (e >> 10) & 3;
  const int v    = (e >> 12) & 1;
  const int r    = (e >> 13) & 1;
  const int m    = ot * 16 + (lane & 15);
  const int ch   = ks * 32 + ((lane >> 4) & 3) * 8 + j;
  const float val = (r ? q2w : q1w)[m * 64 + ch];
  unsigned short h = f2bf(val);
  if (v) h = f2bf(val - __uint_as_float((unsigned)h << 16));
  QWA[e] = h;
}

// ================================================================
// rm_prep: rm (= derived[bb][o*64+m]) -> A-frag order bf16 HI/LO.
// ================================================================
__global__ void rm_prep_kernel(const float* __restrict__ derived,
                               unsigned short* __restrict__ RMA) {
  const int e = blockIdx.x * 256 + threadIdx.x;   // 131072 total
  if (e >= 131072) return;
  const int j    = e & 7;
  const int lane = (e >> 3) & 63;
  const int ks   = (e >> 9) & 1;
  const int ot   = (e >> 10) & 3;
  const int v    = (e >> 12) & 1;
  const int bb   = e >> 13;
  const int o    = ot * 16 + (lane & 15);
  const int m    = ks * 32 + ((lane >> 4) & 3) * 8 + j;
  const float val = derived[(size_t)bb * STATS + o * 64 + m];
  unsigned short h = f2bf(val);
  if (v) h = f2bf(val - __uint_as_float((unsigned)h << 16));
  RMA[e] = h;
}

// ================================================================
// Pass 1 (MFMA stats) — round-14 form (proven best). Unchanged.
// ================================================================
__global__ __launch_bounds__(256, 2) void stats_mfma_kernel(
    const float* __restrict__ t1, const float* __restrict__ t2,
    const float* __restrict__ k1b, const float* __restrict__ v1b,
    const float* __restrict__ k2b, const float* __restrict__ v2b,
    const unsigned short* __restrict__ WK,
    float* __restrict__ partials)
{
  const int chunk = blockIdx.x;
  const int b = blockIdx.y;
  const int r = blockIdx.z;
  const float* x  = (r ? t2 : t1) + (size_t)b * C_ * N_;
  const float* kb = r ? k2b : k1b;
  const float* vb = r ? v2b : v1b;
  const unsigned short* WKr = WK + r * 8192;

  __shared__ unsigned short Xs[64 * 72];
  __shared__ unsigned short Ks[64 * 72];
  __shared__ unsigned short Vs[64 * 72];

  const int t  = threadIdx.x;
  const int w  = t >> 6;
  const int l  = t & 63;
  const int li = l & 15;
  const int g  = l >> 4;

  float kbv[4][4], vbv[4][4];
#pragma unroll
  for (int ot = 0; ot < 4; ++ot)
#pragma unroll
    for (int rg = 0; rg < 4; ++rg) {
      kbv[ot][rg] = kb[ot * 16 + g * 4 + rg];
      vbv[ot][rg] = vb[ot * 16 + g * 4 + rg];
    }

  bf16x8 ones;
#pragma unroll
  for (int j = 0; j < 8; ++j) ones[j] = (short)0x3F80;

  f32x4 accM[4];
#pragma unroll
  for (int ct = 0; ct < 4; ++ct) accM[ct] = (f32x4){0.f, 0.f, 0.f, 0.f};
  f32x4 accSk = (f32x4){0.f, 0.f, 0.f, 0.f};
  f32x4 accSv = (f32x4){0.f, 0.f, 0.f, 0.f};

  for (int it = 0; it < 16; ++it) {
    const int px0 = chunk * 1024 + it * 64;
    __syncthreads();
    {
      const int ch = t >> 2;
      const int ps = t & 3;
      const float* src = x + (size_t)ch * N_ + px0 + ps * 16;
      const float4 f0 = ((const float4*)src)[0];
      const float4 f1 = ((const float4*)src)[1];
      const float4 f2 = ((const float4*)src)[2];
      const float4 f3 = ((const float4*)src)[3];
      float v[16] = {f0.x, f0.y, f0.z, f0.w, f1.x, f1.y, f1.z, f1.w,
                     f2.x, f2.y, f2.z, f2.w, f3.x, f3.y, f3.z, f3.w};
      unsigned short* dst = &Xs[(ps * 16) * 72 + (ch ^ (ps << 4))];
#pragma unroll
      for (int i = 0; i < 16; ++i) dst[i * 72] = f2bf(v[i]);
    }
    __syncthreads();

    bf16x8 bx0 = *(const bf16x8*)&Xs[(w * 16 + li) * 72 + ((g * 8) ^ (w << 4))];
    bf16x8 bx1 = *(const bf16x8*)&Xs[(w * 16 + li) * 72 + ((32 + g * 8) ^ (w << 4))];

    f32x4 ka[4];
#pragma unroll
    for (int ot = 0; ot < 4; ++ot) {
      f32x4 a = (f32x4){0.f, 0.f, 0.f, 0.f};
      const bf16x8 w0 = *(const bf16x8*)(WKr + ((ot * 2 + 0) * 64 + l) * 8);
      const bf16x8 w1 = *(const bf16x8*)(WKr + ((ot * 2 + 1) * 64 + l) * 8);
      a = __builtin_amdgcn_mfma_f32_16x16x32_bf16(w0, bx0, a, 0, 0, 0);
      a = __builtin_amdgcn_mfma_f32_16x16x32_bf16(w1, bx1, a, 0, 0, 0);
      ka[ot] = a;
    }
    float ss = 0.f;
#pragma unroll
    for (int ot = 0; ot < 4; ++ot)
#pragma unroll
      for (int rg = 0; rg < 4; ++rg) {
        const float v2 = ka[ot][rg] + kbv[ot][rg];
        ka[ot][rg] = v2;
        ss += v2 * v2;
      }
    ss += __shfl_xor(ss, 16);
    ss += __shfl_xor(ss, 32);
    const float inv = rsqrtf(ss);
#pragma unroll
    for (int ot = 0; ot < 4; ++ot)
#pragma unroll
      for (int rg = 0; rg < 4; ++rg)
        Ks[(ot * 16 + g * 4 + rg) * 72 + w * 16 + li] = f2bf(ka[ot][rg] * inv);

#pragma unroll
    for (int ot = 0; ot < 4; ++ot) {
      f32x4 a = (f32x4){0.f, 0.f, 0.f, 0.f};
      const bf16x8 w0 = *(const bf16x8*)(WKr + 4096 + ((ot * 2 + 0) * 64 + l) * 8);
      const bf16x8 w1 = *(const bf16x8*)(WKr + 4096 + ((ot * 2 + 1) * 64 + l) * 8);
      a = __builtin_amdgcn_mfma_f32_16x16x32_bf16(w0, bx0, a, 0, 0, 0);
      a = __builtin_amdgcn_mfma_f32_16x16x32_bf16(w1, bx1, a, 0, 0, 0);
#pragma unroll
      for (int rg = 0; rg < 4; ++rg)
        Vs[(ot * 16 + g * 4 + rg) * 72 + w * 16 + li] = f2bf(a[rg] + vbv[ot][rg]);
    }
    __syncthreads();

#pragma unroll
    for (int ks = 0; ks < 2; ++ks) {
      const int ko = ks * 32 + g * 8;
      const bf16x8 aK = *(const bf16x8*)&Ks[(w * 16 + li) * 72 + ko];
      const bf16x8 aV = *(const bf16x8*)&Vs[(w * 16 + li) * 72 + ko];
      accSk = __builtin_amdgcn_mfma_f32_16x16x32_bf16(aK, ones, accSk, 0, 0, 0);
      accSv = __builtin_amdgcn_mfma_f32_16x16x32_bf16(aV, ones, accSv, 0, 0, 0);
#pragma unroll
      for (int ct = 0; ct < 4; ++ct) {
        const bf16x8 bV = *(const bf16x8*)&Vs[(ct * 16 + li) * 72 + ko];
        accM[ct] = __builtin_amdgcn_mfma_f32_16x16x32_bf16(aK, bV, accM[ct], 0, 0, 0);
      }
    }
  }

  float* pb = partials + ((size_t)(r * B_ + b) * CHUNKS + chunk) * STATS;
#pragma unroll
  for (int ct = 0; ct < 4; ++ct)
#pragma unroll
    for (int rg = 0; rg < 4; ++rg)
      pb[(w * 16 + g * 4 + rg) * 64 + ct * 16 + li] = accM[ct][rg];
  if (li == 0) {
#pragma unroll
    for (int rg = 0; rg < 4; ++rg) {
      pb[4096 + w * 16 + g * 4 + rg] = accSk[rg];
      pb[4160 + w * 16 + g * 4 + rg] = accSv[rg];
    }
  }
}

// ================================================================
// Finalize: reduce partials, fold r_w in. (unchanged)
// ================================================================
__global__ void finalize_kernel(const float* __restrict__ partials,
                                const float* __restrict__ r1w,
                                const float* __restrict__ r2w,
                                float* __restrict__ derived)
{
  const int bb = blockIdx.x;
  const int r = bb >> 3;
  const float* rw = r ? r2w : r1w;
  __shared__ float mat[4096];
  __shared__ float ks[64], vs[64];
  const int t = threadIdx.x;
  const float* pb = partials + (size_t)bb * CHUNKS * STATS;
  for (int e = t; e < STATS; e += 256) {
    float s = 0.f;
    for (int j = 0; j < CHUNKS; ++j) s += pb[(size_t)j * STATS + e];
    if (e < 4096) mat[e] = s;
    else if (e < 4160) ks[e - 4096] = s;
    else vs[e - 4160] = s;
  }
  __syncthreads();
  float* der = derived + (size_t)bb * STATS;
  for (int e = t; e < 4096; e += 256) {
    const int o = e >> 6, m = e & 63;
    float s = 0.f;
    for (int c = 0; c < 64; ++c) s += rw[o * 64 + c] * mat[m * 64 + c];
    der[e] = s;
  }
  if (t < 64) {
    float s = 0.f;
    for (int c = 0; c < 64; ++c) s += rw[t * 64 + c] * vs[c];
    der[4096 + t] = s;
    der[4160 + t] = ks[t] + EPSF;
  }
}

// ================================================================
// Pass 2 (MFMA attn) — round-16 form (truncation splits). Unchanged.
// ================================================================
__global__ __launch_bounds__(256, 2) void attn_mfma_kernel(
    const float* __restrict__ t1, const float* __restrict__ t2,
    const float* __restrict__ q1b, const float* __restrict__ q2b,
    const float* __restrict__ r1b, const float* __restrict__ r2b,
    const float* __restrict__ derived,
    const unsigned short* __restrict__ QWA,
    const unsigned short* __restrict__ RMA,
    __hip_bfloat16* __restrict__ catH, __hip_bfloat16* __restrict__ catL)
{
  const int chunk = blockIdx.x;
  const int b = blockIdx.y;
  const int rbr = blockIdx.z;
  const float* x  = (rbr ? t2 : t1) + (size_t)b * C_ * N_;
  const float* qb = rbr ? q2b : q1b;
  const float* rb = rbr ? r2b : r1b;
  const int bb = rbr * B_ + b;
  const float* der = derived + (size_t)bb * STATS;
  const unsigned short* qwa = QWA + rbr * 8192;
  const unsigned short* rma = RMA + (size_t)bb * 8192;

  __shared__ unsigned short XsH[64 * 72];
  __shared__ unsigned short XsL[64 * 72];
  __shared__ unsigned short QsH[64 * 72];
  __shared__ unsigned short QsL[64 * 72];

  const int t  = threadIdx.x;
  const int w  = t >> 6;
  const int l  = t & 63;
  const int li = l & 15;
  const int g  = l >> 4;

  float qbv[16], ksev[16], rvsv[16], rbv[16];
#pragma unroll
  for (int ot = 0; ot < 4; ++ot)
#pragma unroll
    for (int rg = 0; rg < 4; ++rg) {
      const int row = ot * 16 + g * 4 + rg;
      qbv[ot * 4 + rg]  = qb[row];
      ksev[ot * 4 + rg] = der[4160 + row];
      rvsv[ot * 4 + rg] = der[4096 + row];
      rbv[ot * 4 + rg]  = rb[row];
    }

#pragma clang loop unroll(disable)
  for (int it = 0; it < 16; ++it) {
    const int px0 = chunk * 1024 + it * 64;
    __syncthreads();
    {
      const int ch = t >> 2;
      const int ps = t & 3;
      const float* src = x + (size_t)ch * N_ + px0 + ps * 16;
      const float4 f0 = ((const float4*)src)[0];
      const float4 f1v = ((const float4*)src)[1];
      const float4 f2v = ((const float4*)src)[2];
      const float4 f3v = ((const float4*)src)[3];
      float v[16] = {f0.x, f0.y, f0.z, f0.w, f1v.x, f1v.y, f1v.z, f1v.w,
                     f2v.x, f2v.y, f2v.z, f2v.w, f3v.x, f3v.y, f3v.z, f3v.w};
      const int col = ch ^ (ps << 4);
      unsigned short* dH = &XsH[(ps * 16) * 72 + col];
      unsigned short* dL = &XsL[(ps * 16) * 72 + col];
#pragma unroll
      for (int i = 0; i < 16; ++i) {
        const uint2 hl = split2(v[i]);
        dH[i * 72] = (unsigned short)hl.x;
        dL[i * 72] = (unsigned short)hl.y;
      }
    }
    __syncthreads();

    const int rowb = (w * 16 + li) * 72;
    const bf16x8 bxh0 = *(const bf16x8*)&XsH[rowb + ((g * 8) ^ (w << 4))];
    const bf16x8 bxh1 = *(const bf16x8*)&XsH[rowb + ((32 + g * 8) ^ (w << 4))];
    const bf16x8 bxl0 = *(const bf16x8*)&XsL[rowb + ((g * 8) ^ (w << 4))];
    const bf16x8 bxl1 = *(const bf16x8*)&XsL[rowb + ((32 + g * 8) ^ (w << 4))];

    float q[16];
#pragma unroll
    for (int ot = 0; ot < 4; ++ot) {
      f32x4 a = (f32x4){0.f, 0.f, 0.f, 0.f};
      const bf16x8 wh0 = *(const bf16x8*)(qwa + ((0 * 4 + ot) * 2 + 0) * 512 + l * 8);
      const bf16x8 wh1 = *(const bf16x8*)(qwa + ((0 * 4 + ot) * 2 + 1) * 512 + l * 8);
      const bf16x8 wl0 = *(const bf16x8*)(qwa + ((1 * 4 + ot) * 2 + 0) * 512 + l * 8);
      const bf16x8 wl1 = *(const bf16x8*)(qwa + ((1 * 4 + ot) * 2 + 1) * 512 + l * 8);
      a = __builtin_amdgcn_mfma_f32_16x16x32_bf16(wh0, bxh0, a, 0, 0, 0);
      a = __builtin_amdgcn_mfma_f32_16x16x32_bf16(wh1, bxh1, a, 0, 0, 0);
      a = __builtin_amdgcn_mfma_f32_16x16x32_bf16(wh0, bxl0, a, 0, 0, 0);
      a = __builtin_amdgcn_mfma_f32_16x16x32_bf16(wh1, bxl1, a, 0, 0, 0);
      a = __builtin_amdgcn_mfma_f32_16x16x32_bf16(wl0, bxh0, a, 0, 0, 0);
      a = __builtin_amdgcn_mfma_f32_16x16x32_bf16(wl1, bxh1, a, 0, 0, 0);
#pragma unroll
      for (int rg = 0; rg < 4; ++rg) q[ot * 4 + rg] = a[rg] + qbv[ot * 4 + rg];
    }

    float ss = 0.f, d = 0.f;
#pragma unroll
    for (int i = 0; i < 16; ++i) { ss += q[i] * q[i]; d += q[i] * ksev[i]; }
    ss += __shfl_xor(ss, 16);  ss += __shfl_xor(ss, 32);
    d  += __shfl_xor(d, 16);   d  += __shfl_xor(d, 32);
    const float inv = rsqrtf(ss);
    const float rden = 1.0f / (65536.0f + inv * d);
    const float f1 = rden * inv;

#pragma unroll
    for (int ot = 0; ot < 4; ++ot) {
      const uint2 s0 = split2(q[ot * 4 + 0]);
      const uint2 s1 = split2(q[ot * 4 + 1]);
      const uint2 s2 = split2(q[ot * 4 + 2]);
      const uint2 s3 = split2(q[ot * 4 + 3]);
      const int off = (w * 16 + li) * 72 + ot * 16 + g * 4;
      *(uint2*)&QsH[off] = make_uint2(s0.x | (s1.x << 16), s2.x | (s3.x << 16));
      *(uint2*)&QsL[off] = make_uint2(s0.y | (s1.y << 16), s2.y | (s3.y << 16));
    }

    const bf16x8 bqh0 = *(const bf16x8*)&QsH[rowb + g * 8];
    const bf16x8 bqh1 = *(const bf16x8*)&QsH[rowb + 32 + g * 8];
    const bf16x8 bql0 = *(const bf16x8*)&QsL[rowb + g * 8];
    const bf16x8 bql1 = *(const bf16x8*)&QsL[rowb + 32 + g * 8];

#pragma unroll
    for (int ot = 0; ot < 4; ++ot) {
      f32x4 a = (f32x4){0.f, 0.f, 0.f, 0.f};
      const bf16x8 rh0 = *(const bf16x8*)(rma + ((0 * 4 + ot) * 2 + 0) * 512 + l * 8);
      const bf16x8 rh1 = *(const bf16x8*)(rma + ((0 * 4 + ot) * 2 + 1) * 512 + l * 8);
      const bf16x8 rl0 = *(const bf16x8*)(rma + ((1 * 4 + ot) * 2 + 0) * 512 + l * 8);
      const bf16x8 rl1 = *(const bf16x8*)(rma + ((1 * 4 + ot) * 2 + 1) * 512 + l * 8);
      a = __builtin_amdgcn_mfma_f32_16x16x32_bf16(rh0, bqh0, a, 0, 0, 0);
      a = __builtin_amdgcn_mfma_f32_16x16x32_bf16(rh1, bqh1, a, 0, 0, 0);
      a = __builtin_amdgcn_mfma_f32_16x16x32_bf16(rh0, bql0, a, 0, 0, 0);
      a = __builtin_amdgcn_mfma_f32_16x16x32_bf16(rh1, bql1, a, 0, 0, 0);
      a = __builtin_amdgcn_mfma_f32_16x16x32_bf16(rl0, bqh0, a, 0, 0, 0);
      a = __builtin_amdgcn_mfma_f32_16x16x32_bf16(rl1, bqh1, a, 0, 0, 0);

      const float a0 = f1 * a[0] + rden * rvsv[ot * 4 + 0] + rbv[ot * 4 + 0];
      const float a1 = f1 * a[1] + rden * rvsv[ot * 4 + 1] + rbv[ot * 4 + 1];
      const float a2 = f1 * a[2] + rden * rvsv[ot * 4 + 2] + rbv[ot * 4 + 2];
      const float a3 = f1 * a[3] + rden * rvsv[ot * 4 + 3] + rbv[ot * 4 + 3];
      const uint2 s0 = split2(a0);
      const uint2 s1 = split2(a1);
      const uint2 s2 = split2(a2);
      const uint2 s3 = split2(a3);
      const size_t base =
          (((size_t)(b * 8 + rbr * 4 + ot)) * N_ + (px0 + w * 16 + li)) * 16 + g * 4;
      *(uint2*)(catH + base) = make_uint2(s0.x | (s1.x << 16), s2.x | (s3.x << 16));
      *(uint2*)(catL + base) = make_uint2(s0.y | (s1.y << 16), s2.y | (s3.y << 16));
    }
  }
}

// ================================================================
// prep_wa: conv weights -> A-frag order, split bf16 hi/lo. (unchanged)
// ================================================================
__global__ void prep_wa_kernel(const float* __restrict__ cw,
                               __hip_bfloat16* __restrict__ WA) {
  const int e = blockIdx.x * 256 + threadIdx.x;
  if (e >= 8 * 5 * 2 * 4 * 512) return;
  const int j    = e & 7;
  const int lane = (e >> 3) & 63;
  const int f    = e >> 9;
  const int ot   = f & 3;
  const int v    = (f >> 2) & 1;
  const int s    = (f >> 3) % 5;
  const int c    = (f >> 3) / 5;
  const int o    = ot * 16 + (lane & 15);
  const int g    = lane >> 4;
  const int tap  = 2 * s + (g >> 1);
  float val = 0.f;
  if (tap <= 8) {
    const int ci = c * 16 + (g & 1) * 8 + j;
    val = cw[(size_t)(o * 128 + ci) * 9 + tap];
  }
  __hip_bfloat16 h = __float2bfloat16(val);
  if (v) h = __float2bfloat16(val - __bfloat162float(h));
  WA[e] = h;
}

// ================================================================
// Pass 3: 3x3 conv via MFMA implicit GEMM, split-bf16, LDS dbuf,
// (row, ot-half) wave split.
// ROUND-18: software-pipeline the A-frag loads one s-step ahead
// (named regs, +32 VGPR, still 128-class). Rationale: VGPR=60 showed
// the compiler issues each s-step's 4 L2 loads right before their
// MFMAs (~200cy exposed head on every s-step; MFMA issue/step is
// only ~116cy) -> MfmaUtil capped ~51%. Now s+1's loads are issued
// before s's MFMA cluster and consumed a full step later.
// ================================================================
__global__ __launch_bounds__(512, 4) void conv_mfma_kernel(
    const __hip_bfloat16* __restrict__ catH,
    const __hip_bfloat16* __restrict__ catL,
    const __hip_bfloat16* __restrict__ WA,
    const float* __restrict__ cb,
    float* __restrict__ out)
{
  __shared__ __hip_bfloat16 XsH[2][6 * 68 * 24];
  __shared__ __hip_bfloat16 XsL[2][6 * 68 * 24];

  const int t  = threadIdx.x;
  const int v  = t >> 6;        // wave id 0..7
  const int wr = v >> 1;        // output row 0..3
  const int oh = v & 1;         // ot-half: ots {2oh, 2oh+1}
  const int l  = t & 63;
  const int li = l & 15;
  const int g  = l >> 4;
  const int x0 = blockIdx.x * 64;
  const int y0 = blockIdx.y * 4;
  const int b  = blockIdx.z;

  const bool hasA = (t < 396);
  const int rA = t / 66, cA = t - rA * 66;
  const int gyA = y0 + rA - 1, gxA = x0 + cA - 1;
  const bool okA = hasA && ((unsigned)gyA < 256u) && ((unsigned)gxA < 256u);
  const size_t offA = ((size_t)(gyA * HW_ + gxA)) * 16;
  const int leA = (rA * 68 + cA) * 24;
  const uint4 Z = make_uint4(0u, 0u, 0u, 0u);

  uint4 Ah0, Ah1, Al0, Al1;

  f32x4 acc[2][4];
#pragma unroll
  for (int i = 0; i < 2; ++i)
#pragma unroll
    for (int k = 0; k < 4; ++k) acc[i][k] = (f32x4){0.f, 0.f, 0.f, 0.f};

  {
    const size_t chb = ((size_t)(b * 8 + 0)) * N_ * 16;
    Ah0 = Ah1 = Al0 = Al1 = Z;
    if (okA) {
      const uint4* ph = (const uint4*)(catH + chb + offA);
      Ah0 = ph[0]; Ah1 = ph[1];
      const uint4* pl = (const uint4*)(catL + chb + offA);
      Al0 = pl[0]; Al1 = pl[1];
    }
  }

  for (int c = 0; c < 8; ++c) {
    const int cur = c & 1;
    // ---- write-late: staged regs (chunk c) -> buf[cur]
    if (hasA) {
      *(uint4*)(&XsH[cur][leA]) = Ah0; *(uint4*)(&XsH[cur][leA + 8]) = Ah1;
      *(uint4*)(&XsL[cur][leA]) = Al0; *(uint4*)(&XsL[cur][leA + 8]) = Al1;
    }
    __syncthreads();             // buf[cur] visible to all waves
    // ---- issue-early: chunk c+1 loads overlap COMPUTE(c)
    if (c < 7) {
      const size_t chb = ((size_t)(b * 8 + c + 1)) * N_ * 16;
      Ah0 = Ah1 = Al0 = Al1 = Z;
      if (okA) {
        const uint4* ph = (const uint4*)(catH + chb + offA);
        Ah0 = ph[0]; Ah1 = ph[1];
        const uint4* pl = (const uint4*)(catL + chb + offA);
        Al0 = pl[0]; Al1 = pl[1];
      }
    }

    // ---- COMPUTE(c): this wave covers ots {2oh, 2oh+1}, 4 pt
    const __hip_bfloat16* xh = XsH[cur];
    const __hip_bfloat16* xl = XsL[cur];
    const __hip_bfloat16* wa_b = WA + (size_t)c * 20480 + l * 8 + oh * 1024;

    // A-frag software pipeline: preload s=0
    bf16x8 cH0 = *(const bf16x8*)(wa_b + 0);
    bf16x8 cH1 = *(const bf16x8*)(wa_b + 512);
    bf16x8 cL0 = *(const bf16x8*)(wa_b + 2048);
    bf16x8 cL1 = *(const bf16x8*)(wa_b + 2560);

#pragma unroll
    for (int s = 0; s < 5; ++s) {
      bf16x8 nH0, nH1, nL0, nL1;
      if (s < 4) {               // issue s+1 loads before s's MFMAs
        const __hip_bfloat16* wn = wa_b + (s + 1) * 4096;
        nH0 = *(const bf16x8*)(wn + 0);
        nH1 = *(const bf16x8*)(wn + 512);
        nL0 = *(const bf16x8*)(wn + 2048);
        nL1 = *(const bf16x8*)(wn + 2560);
      }

      int tap = 2 * s + (g >> 1);
      if (tap > 8) tap = 0;
      const int ky = tap / 3;
      const int kx = tap - ky * 3;
      const int e0 = ((wr + ky) * 68 + li + kx) * 24 + (g & 1) * 8;

#pragma unroll
      for (int pt = 0; pt < 4; ++pt) {
        const bf16x8 bH = *(const bf16x8*)(&xh[e0 + pt * 384]);
        const bf16x8 bL = *(const bf16x8*)(&xl[e0 + pt * 384]);
        acc[0][pt] = __builtin_amdgcn_mfma_f32_16x16x32_bf16(cH0, bH, acc[0][pt], 0, 0, 0);
        acc[0][pt] = __builtin_amdgcn_mfma_f32_16x16x32_bf16(cH0, bL, acc[0][pt], 0, 0, 0);
        acc[0][pt] = __builtin_amdgcn_mfma_f32_16x16x32_bf16(cL0, bH, acc[0][pt], 0, 0, 0);
        acc[1][pt] = __builtin_amdgcn_mfma_f32_16x16x32_bf16(cH1, bH, acc[1][pt], 0, 0, 0);
        acc[1][pt] = __builtin_amdgcn_mfma_f32_16x16x32_bf16(cH1, bL, acc[1][pt], 0, 0, 0);
        acc[1][pt] = __builtin_amdgcn_mfma_f32_16x16x32_bf16(cL1, bH, acc[1][pt], 0, 0, 0);
      }

      if (s < 4) { cH0 = nH0; cH1 = nH1; cL0 = nL0; cL1 = nL1; }
    }
  }

#pragma unroll
  for (int oi = 0; oi < 2; ++oi)
#pragma unroll
    for (int r = 0; r < 4; ++r) {
      const int o = (oh * 2 + oi) * 16 + g * 4 + r;
      const float bv = cb[o];
      float* orow = out + ((size_t)b * 64 + o) * N_ + (size_t)(y0 + wr) * HW_ + x0 + li;
#pragma unroll
      for (int pt = 0; pt < 4; ++pt)
        orow[pt * 16] = acc[oi][pt][r] + bv;
    }
}

// ================================================================
extern "C" void kernel_launch(void* const* d_in, const int* in_sizes, int n_in,
                              void* d_out, int out_size, void* d_ws, size_t ws_size,
                              hipStream_t stream) {
  const float* t1  = (const float*)d_in[0];
  const float* t2  = (const float*)d_in[1];
  const float* q1w = (const float*)d_in[2];
  const float* q1b = (const float*)d_in[3];
  const float* k1w = (const float*)d_in[4];
  const float* k1b = (const float*)d_in[5];
  const float* v1w = (const float*)d_in[6];
  const float* v1b = (const float*)d_in[7];
  const float* r1w = (const float*)d_in[8];
  const float* r1b = (const float*)d_in[9];
  const float* q2w = (const float*)d_in[10];
  const float* q2b = (const float*)d_in[11];
  const float* k2w = (const float*)d_in[12];
  const float* k2b = (const float*)d_in[13];
  const float* v2w = (const float*)d_in[14];
  const float* v2b = (const float*)d_in[15];
  const float* r2w = (const float*)d_in[16];
  const float* r2b = (const float*)d_in[17];
  const float* cw  = (const float*)d_in[18];
  const float* cbp = (const float*)d_in[19];
  float* out = (float*)d_out;

  // ws: [catH 128MB][catL 128MB][partials 16.5MB][derived 264KB]
  // Aliases inside the dead-after-finalize partials region:
  //   WA at +0 (320KB), RMA at +1MB (256KB), QWA at +2MB (32KB).
  // WK (stats weights) aliases catH (dead until attn runs).
  char* ws = (char*)d_ws;
  const size_t catB  = (size_t)B_ * 8 * N_ * 16 * 2;     // 128 MB each
  const size_t partB = (size_t)16 * CHUNKS * STATS * sizeof(float);
  __hip_bfloat16* catHp = (__hip_bfloat16*)ws;
  __hip_bfloat16* catLp = (__hip_bfloat16*)(ws + catB);
  float* part = (float*)(ws + 2 * catB);
  float* der  = (float*)(ws + 2 * catB + partB);
  __hip_bfloat16* WA   = (__hip_bfloat16*)part;                         // alias
  unsigned short* RMAp = (unsigned short*)(ws + 2 * catB + (1u << 20)); // alias
  unsigned short* QWAp = (unsigned short*)(ws + 2 * catB + (2u << 20)); // alias
  unsigned short* WKp  = (unsigned short*)ws;                           // alias (catH)

  prep_proj_kernel<<<dim3(64), 256, 0, stream>>>(k1w, v1w, k2w, v2w, WKp);
  stats_mfma_kernel<<<dim3(CHUNKS, B_, 2), 256, 0, stream>>>(
      t1, t2, k1b, v1b, k2b, v2b, WKp, part);
  finalize_kernel<<<dim3(16), 256, 0, stream>>>(part, r1w, r2w, der);
  qw_prep_kernel<<<dim3(64), 256, 0, stream>>>(q1w, q2w, QWAp);
  rm_prep_kernel<<<dim3(512), 256, 0, stream>>>(der, RMAp);
  prep_wa_kernel<<<dim3(640), 256, 0, stream>>>(cw, WA);
  attn_mfma_kernel<<<dim3(CHUNKS, B_, 2), 256, 0, stream>>>(
      t1, t2, q1b, q2b, r1b, r2b, der, QWAp, RMAp, catHp, catLp);
  conv_mfma_kernel<<<dim3(4, 64, B_), 512, 0, stream>>>(
      catHp, catLp, WA, cbp, out);
}